// Round 11
// baseline (249.025 us; speedup 1.0000x reference)
//
#include <hip/hip_runtime.h>

// GCN 2-layer: N=100000, E=3200000, IN=8, HID=64, OUT=1.
// Round 11: occupancy everywhere. R9/R10 both ran kA_scatter with 4000 waves
// (device capacity 8192) -> 49% cap, 23% avg, 56us both. Fixes:
//   hist/scatter: 512-thr blocks x 1000 chunks = 8000 waves.
//   sortdeg: no 'sorted' LDS buffer (direct segment-local global scatter,
//     L2-resident lines), deg via wave-private LDS f32 bins: 49->27 KB LDS,
//     3->6 blocks/CU.
//   kB2/kB3: 2 threads/node, pair reduce via shfl_xor, MLP j-split.

#define N_    100000
#define E_    3200000
#define BK    2048        // buckets = col >> 6 (64 nodes/bucket)
#define NBUCK 1563        // ceil(N_/64)
#define CA    1000        // phase-A edge chunks
#define CSA   3200        // E_/CA
#define GG    8           // chunk groups
#define GCH   125         // chunks per group
#define CAP   3072        // per-bucket LDS edge capacity (mean 2048, sd ~45)
#define NBLK  391         // ceil(N_/256)

// ---- A1: per-(chunk,bucket) histogram. countsA chunk-major [c][b].
__global__ void kA_hist(const int* __restrict__ col, int* __restrict__ countsA) {
    __shared__ int bins[BK];
    int c = blockIdx.x, t = threadIdx.x;
    for (int i = t; i < BK; i += 512) bins[i] = 0;
    __syncthreads();
    const int* cp = col + c * CSA;
    {   // 4-wide: edges t+{0,512,1024,1536}
        int v0 = cp[t], v1 = cp[t + 512], v2 = cp[t + 1024], v3 = cp[t + 1536];
        atomicAdd(&bins[v0 >> 6], 1);
        atomicAdd(&bins[v1 >> 6], 1);
        atomicAdd(&bins[v2 >> 6], 1);
        atomicAdd(&bins[v3 >> 6], 1);
    }
    {   // 2-wide: t+{2048,2560}
        int v0 = cp[t + 2048], v1 = cp[t + 2560];
        atomicAdd(&bins[v0 >> 6], 1);
        atomicAdd(&bins[v1 >> 6], 1);
    }
    if (t < 128) atomicAdd(&bins[cp[3072 + t] >> 6], 1);
    __syncthreads();
    int* outp = countsA + (size_t)c * BK;
    for (int i = t; i < BK; i += 512) outp[i] = bins[i];
}

// ---- A2a: within-group exclusive prefix across chunks.
__global__ void kA_scan1(int* __restrict__ countsA, int* __restrict__ grptot) {
    int tid = blockIdx.x * 256 + threadIdx.x;   // 16384 threads
    int g = tid >> 11;
    int b = tid & (BK - 1);
    int c0 = g * GCH;
    int run = 0;
    #pragma unroll 5
    for (int k = 0; k < GCH; k++) {
        size_t idx = (size_t)(c0 + k) * BK + b;
        int v = countsA[idx];
        countsA[idx] = run;
        run += v;
    }
    grptot[g * BK + b] = run;
}

// ---- A2b (one block): scan grptot across groups, bucket-base scan, fold.
__global__ void kA_scan2B(int* __restrict__ grptot, int* __restrict__ baseB) {
    __shared__ int sm[1024];
    int t = threadIdx.x;
    int tot0, tot1;
    {
        int b = 2 * t, run = 0;
        #pragma unroll
        for (int g = 0; g < GG; g++) {
            int idx = g * BK + b;
            int v = grptot[idx];
            grptot[idx] = run;
            run += v;
        }
        tot0 = run;
    }
    {
        int b = 2 * t + 1, run = 0;
        #pragma unroll
        for (int g = 0; g < GG; g++) {
            int idx = g * BK + b;
            int v = grptot[idx];
            grptot[idx] = run;
            run += v;
        }
        tot1 = run;
    }
    int pair = tot0 + tot1;
    sm[t] = pair;
    __syncthreads();
    for (int off = 1; off < 1024; off <<= 1) {
        int add = (t >= off) ? sm[t - off] : 0;
        __syncthreads();
        sm[t] += add;
        __syncthreads();
    }
    int excl = sm[t] - pair;
    baseB[2 * t]     = excl;
    baseB[2 * t + 1] = excl + tot0;
    if (t == 1023) baseB[BK] = sm[1023];
    #pragma unroll
    for (int g = 0; g < GG; g++) {
        grptot[g * BK + 2 * t]     += excl;
        grptot[g * BK + 2 * t + 1] += excl + tot0;
    }
}

// ---- A3: scatter packed records {row|lc<<17, w} into bucket segments
__global__ void kA_scatter(const int* __restrict__ row, const int* __restrict__ col,
                           const float* __restrict__ w,
                           const int* __restrict__ countsA, const int* __restrict__ grptot,
                           int2* __restrict__ brec) {
    __shared__ int curs[BK];
    int c = blockIdx.x, t = threadIdx.x;
    int g = c / GCH;
    const int* pc = countsA + (size_t)c * BK;
    const int* go = grptot + g * BK;
    for (int i = t; i < BK; i += 512) curs[i] = go[i] + pc[i];
    __syncthreads();
    const int* cp = col + c * CSA;
    const int* rp = row + c * CSA;
    const float* wp = w + c * CSA;
    {   // 4-wide
        int e0 = t, e1 = t + 512, e2 = t + 1024, e3 = t + 1536;
        int v0 = cp[e0], v1 = cp[e1], v2 = cp[e2], v3 = cp[e3];
        int r0 = rp[e0], r1 = rp[e1], r2 = rp[e2], r3 = rp[e3];
        float w0 = wp[e0], w1 = wp[e1], w2 = wp[e2], w3 = wp[e3];
        int p0 = atomicAdd(&curs[v0 >> 6], 1);
        brec[p0] = make_int2(r0 | ((v0 & 63) << 17), __float_as_int(w0));
        int p1 = atomicAdd(&curs[v1 >> 6], 1);
        brec[p1] = make_int2(r1 | ((v1 & 63) << 17), __float_as_int(w1));
        int p2 = atomicAdd(&curs[v2 >> 6], 1);
        brec[p2] = make_int2(r2 | ((v2 & 63) << 17), __float_as_int(w2));
        int p3 = atomicAdd(&curs[v3 >> 6], 1);
        brec[p3] = make_int2(r3 | ((v3 & 63) << 17), __float_as_int(w3));
    }
    {   // 2-wide
        int e0 = t + 2048, e1 = t + 2560;
        int v0 = cp[e0], v1 = cp[e1];
        int r0 = rp[e0], r1 = rp[e1];
        float w0 = wp[e0], w1 = wp[e1];
        int p0 = atomicAdd(&curs[v0 >> 6], 1);
        brec[p0] = make_int2(r0 | ((v0 & 63) << 17), __float_as_int(w0));
        int p1 = atomicAdd(&curs[v1 >> 6], 1);
        brec[p1] = make_int2(r1 | ((v1 & 63) << 17), __float_as_int(w1));
    }
    if (t < 128) {
        int e2 = 3072 + t;
        int v = cp[e2];
        int pos = atomicAdd(&curs[v >> 6], 1);
        brec[pos] = make_int2(rp[e2] | ((v & 63) << 17), __float_as_int(wp[e2]));
    }
}

// ---- B-sort: per-bucket counting sort -> per-node CSR + deg + dinv + xw.
//   Sorted records written straight to global (segment stays in L2).
__global__ void kB_sortdeg(const int* __restrict__ baseB, int2* __restrict__ brec,
                           const float* __restrict__ x,
                           float* __restrict__ dinv, float* __restrict__ xw,
                           int* __restrict__ nodeptr) {
    __shared__ int2  raw[CAP];         // 24 KB
    __shared__ int   h[4 * 64];
    __shared__ float degw[4 * 64];
    __shared__ int   nb[65];
    int b = blockIdx.x, t = threadIdx.x;
    int wid = t >> 6;
    int st = baseB[b];
    int cnt = baseB[b + 1] - st;
    if (cnt > CAP) cnt = CAP;          // statistically impossible; guard
    h[t] = 0;
    degw[t] = 0.0f;
    __syncthreads();
    int i = t;
    for (; i + 768 < cnt; i += 1024) {
        int2 q0 = brec[st + i],       q1 = brec[st + i + 256];
        int2 q2 = brec[st + i + 512], q3 = brec[st + i + 768];
        raw[i] = q0; raw[i + 256] = q1; raw[i + 512] = q2; raw[i + 768] = q3;
        int hb = wid << 6;
        atomicAdd(&h[hb + (q0.x >> 17)], 1);
        atomicAdd(&h[hb + (q1.x >> 17)], 1);
        atomicAdd(&h[hb + (q2.x >> 17)], 1);
        atomicAdd(&h[hb + (q3.x >> 17)], 1);
        atomicAdd(&degw[hb + (q0.x >> 17)], __int_as_float(q0.y));
        atomicAdd(&degw[hb + (q1.x >> 17)], __int_as_float(q1.y));
        atomicAdd(&degw[hb + (q2.x >> 17)], __int_as_float(q2.y));
        atomicAdd(&degw[hb + (q3.x >> 17)], __int_as_float(q3.y));
    }
    for (; i < cnt; i += 256) {
        int2 q = brec[st + i];
        raw[i] = q;
        atomicAdd(&h[(wid << 6) + (q.x >> 17)], 1);
        atomicAdd(&degw[(wid << 6) + (q.x >> 17)], __int_as_float(q.y));
    }
    __syncthreads();
    if (t < 64) {
        int off = 0;
        #pragma unroll
        for (int w2 = 0; w2 < 4; w2++) {
            int cc = h[(w2 << 6) + t];
            h[(w2 << 6) + t] = off;
            off += cc;
        }
        int val = off;
        #pragma unroll
        for (int d = 1; d < 64; d <<= 1) {
            int u = __shfl_up(val, d);
            if (t >= d) val += u;
        }
        nb[t] = val - off;
        if (t == 63) nb[64] = val;
    }
    __syncthreads();
    if (t < 64) {
        int e2 = nb[t];
        #pragma unroll
        for (int w2 = 0; w2 < 4; w2++) h[(w2 << 6) + t] += e2;
    }
    __syncthreads();
    for (int j = t; j < cnt; j += 256) {
        int2 q = raw[j];
        int lc = q.x >> 17;
        int pos = atomicAdd(&h[(wid << 6) + lc], 1);
        brec[st + pos] = make_int2(q.x & 0x1FFFF, q.y);   // direct, L2-local
    }
    // node outputs (reads degw/nb only — no sync needed with scatter loop)
    if (t < 64) {
        int n = (b << 6) + t;
        if (n < N_) {
            float d = degw[t] + degw[64 + t] + degw[128 + t] + degw[192 + t];
            float di = rsqrtf(d + 1.0f);
            dinv[n] = di;
            nodeptr[n] = st + nb[t];
            const float4* xi = (const float4*)(x + (size_t)n * 8);
            float4 xa = xi[0], xb = xi[1];
            float4* o = (float4*)(xw + (size_t)n * 8);
            o[0] = make_float4(di * xa.x, di * xa.y, di * xa.z, di * xa.w);
            o[1] = make_float4(di * xb.x, di * xb.y, di * xb.z, di * xb.w);
        }
        if (b == NBUCK - 1 && t == 0) nodeptr[N_] = E_;
    }
}

// ---- B2: 2 threads/node register aggregation + split MLP. Zero atomics.
__global__ void kB2_node(const int* __restrict__ nodeptr, const int2* __restrict__ srec,
                         const float* __restrict__ dinv,
                         const float* __restrict__ xw,
                         const float* __restrict__ W1,
                         const float* __restrict__ b1,
                         const float* __restrict__ W2,
                         float* __restrict__ tv) {
    __shared__ float sW1[8 * 64];
    __shared__ float sb1[64];
    __shared__ float sW2[64];
    int t = threadIdx.x;                  // 512 threads
    sW1[t] = W1[t];
    if (t < 64) { sb1[t] = b1[t]; sW2[t] = W2[t]; }
    __syncthreads();
    int n = blockIdx.x * 256 + (t >> 1);
    int half = t & 1;
    if (n >= N_) return;
    int st = nodeptr[n], en = nodeptr[n + 1];
    const float4* xw4 = (const float4*)xw;
    float a[8];
    if (half == 0) {
        float4 s0 = xw4[2 * n], s1 = xw4[2 * n + 1];
        a[0] = s0.x; a[1] = s0.y; a[2] = s0.z; a[3] = s0.w;
        a[4] = s1.x; a[5] = s1.y; a[6] = s1.z; a[7] = s1.w;
    } else {
        #pragma unroll
        for (int k = 0; k < 8; k++) a[k] = 0.0f;
    }
    int e = st + half;
    for (; e + 2 < en; e += 4) {          // 2 edges per iter (stride 2)
        int2 q0 = srec[e], q1 = srec[e + 2];
        float4 f0a = xw4[2 * q0.x], f0b = xw4[2 * q0.x + 1];
        float4 f1a = xw4[2 * q1.x], f1b = xw4[2 * q1.x + 1];
        float w0 = __int_as_float(q0.y), w1 = __int_as_float(q1.y);
        a[0] = fmaf(w0, f0a.x, a[0]); a[1] = fmaf(w0, f0a.y, a[1]);
        a[2] = fmaf(w0, f0a.z, a[2]); a[3] = fmaf(w0, f0a.w, a[3]);
        a[4] = fmaf(w0, f0b.x, a[4]); a[5] = fmaf(w0, f0b.y, a[5]);
        a[6] = fmaf(w0, f0b.z, a[6]); a[7] = fmaf(w0, f0b.w, a[7]);
        a[0] = fmaf(w1, f1a.x, a[0]); a[1] = fmaf(w1, f1a.y, a[1]);
        a[2] = fmaf(w1, f1a.z, a[2]); a[3] = fmaf(w1, f1a.w, a[3]);
        a[4] = fmaf(w1, f1b.x, a[4]); a[5] = fmaf(w1, f1b.y, a[5]);
        a[6] = fmaf(w1, f1b.z, a[6]); a[7] = fmaf(w1, f1b.w, a[7]);
    }
    if (e < en) {
        int2 q = srec[e];
        float4 fa = xw4[2 * q.x], fb = xw4[2 * q.x + 1];
        float w0 = __int_as_float(q.y);
        a[0] = fmaf(w0, fa.x, a[0]); a[1] = fmaf(w0, fa.y, a[1]);
        a[2] = fmaf(w0, fa.z, a[2]); a[3] = fmaf(w0, fa.w, a[3]);
        a[4] = fmaf(w0, fb.x, a[4]); a[5] = fmaf(w0, fb.y, a[5]);
        a[6] = fmaf(w0, fb.z, a[6]); a[7] = fmaf(w0, fb.w, a[7]);
    }
    // pair-reduce a[] across the 2 lanes of this node
    #pragma unroll
    for (int k = 0; k < 8; k++) a[k] += __shfl_xor(a[k], 1);
    float di = dinv[n];
    #pragma unroll
    for (int k = 0; k < 8; k++) a[k] *= di;
    // split MLP: half 0 -> j=0..31, half 1 -> j=32..63
    float sv = 0.0f;
    int jb = half << 5;
    #pragma unroll
    for (int j = 0; j < 32; j++) {
        int jj = jb + j;
        float h = sb1[jj];
        #pragma unroll
        for (int k = 0; k < 8; k++) h = fmaf(a[k], sW1[k * 64 + jj], h);
        sv = fmaf(fmaxf(h, 0.0f), sW2[jj], sv);
    }
    sv += __shfl_xor(sv, 1);
    if (half == 0) tv[n] = di * sv;
}

// ---- B3: 2 threads/node layer-2. out = b2 + dinv[n]*(tv[n] + sum w*tv[r])
__global__ void kB3_node(const int* __restrict__ nodeptr, const int2* __restrict__ srec,
                         const float* __restrict__ dinv,
                         const float* __restrict__ tv,
                         const float* __restrict__ b2,
                         float* __restrict__ out) {
    int t = threadIdx.x;                  // 512 threads
    int n = blockIdx.x * 256 + (t >> 1);
    int half = t & 1;
    if (n >= N_) return;
    int st = nodeptr[n], en = nodeptr[n + 1];
    float acc = (half == 0) ? tv[n] : 0.0f;
    int e = st + half;
    for (; e + 6 < en; e += 8) {          // 4 edges per iter (stride 2)
        int2 q0 = srec[e], q1 = srec[e + 2], q2 = srec[e + 4], q3 = srec[e + 6];
        float t0 = tv[q0.x], t1 = tv[q1.x], t2 = tv[q2.x], t3 = tv[q3.x];
        acc = fmaf(__int_as_float(q0.y), t0, acc);
        acc = fmaf(__int_as_float(q1.y), t1, acc);
        acc = fmaf(__int_as_float(q2.y), t2, acc);
        acc = fmaf(__int_as_float(q3.y), t3, acc);
    }
    for (; e < en; e += 2) {
        int2 q = srec[e];
        acc = fmaf(__int_as_float(q.y), tv[q.x], acc);
    }
    acc += __shfl_xor(acc, 1);
    if (half == 0) out[n] = b2[0] + dinv[n] * acc;
}

extern "C" void kernel_launch(void* const* d_in, const int* in_sizes, int n_in,
                              void* d_out, int out_size, void* d_ws, size_t ws_size,
                              hipStream_t stream) {
    const float* x  = (const float*)d_in[0];
    const int*   ei = (const int*)d_in[1];    // [2, E] int32
    const float* w  = (const float*)d_in[2];
    const float* W1 = (const float*)d_in[3];
    const float* b1 = (const float*)d_in[4];
    const float* W2 = (const float*)d_in[5];
    const float* b2 = (const float*)d_in[6];
    float* out = (float*)d_out;

    const int* row = ei;
    const int* col = ei + E_;

    // ws (ints): countsA[CA*BK]=2048000 | grptot[GG*BK]=16384 |
    //   baseB[2049 pad 2560] | nodeptr[100352] | dinv[N] | xw[8N] | tv[N] |
    //   brec[E] int2                                   ~38.3 MB
    int*   wsI     = (int*)d_ws;
    int*   countsA = wsI;
    int*   grptot  = wsI + (size_t)CA * BK;          // 2048000
    int*   baseB   = grptot + GG * BK;               // +16384
    int*   nodeptr = baseB + 2560;
    float* dinv    = (float*)(nodeptr + 100352);
    float* xw      = dinv + N_;
    float* tv      = xw + (size_t)8 * N_;
    int2*  brec    = (int2*)(tv + N_);

    kA_hist   <<<CA, 512, 0, stream>>>(col, countsA);
    kA_scan1  <<<64, 256, 0, stream>>>(countsA, grptot);
    kA_scan2B <<<1, 1024, 0, stream>>>(grptot, baseB);
    kA_scatter<<<CA, 512, 0, stream>>>(row, col, w, countsA, grptot, brec);
    kB_sortdeg<<<NBUCK, 256, 0, stream>>>(baseB, brec, x, dinv, xw, nodeptr);
    kB2_node  <<<NBLK, 512, 0, stream>>>(nodeptr, brec, dinv, xw, W1, b1, W2, tv);
    kB3_node  <<<NBLK, 512, 0, stream>>>(nodeptr, brec, dinv, tv, b2, out);
}

// Round 12
// 236.911 us; speedup vs baseline: 1.0511x; 1.0511x over previous
//
#include <hip/hip_runtime.h>

// GCN 2-layer: N=100000, E=3200000, IN=8, HID=64, OUT=1.
// Round 12: run-coalesced scatter. R9-R11 showed kA_scatter pinned at
// ~55-60us regardless of occupancy (23->40%) or ILP: bound by 3.2M fully
// random 8B stores (1 L2 transaction / 32B sector each, WRITE 85MB).
// kA_scatter2: each block owns 12800 edges (4 hist-chunks, order within a
// bucket is irrelevant -> combined range is valid), sorts them by bucket in
// LDS (146KB: recs + u16 bucket ids + bins), then writes runs (avg 6.25
// edges = 50B) contiguously: dst = shift[b] + j.

#define N_    100000
#define E_    3200000
#define BK    2048        // buckets = col >> 6 (64 nodes/bucket)
#define NBUCK 1563        // ceil(N_/64)
#define CA    1000        // hist chunks
#define CSA   3200        // E_/CA
#define GG    10          // chunk groups (GCH multiple of 4!)
#define GCH   100         // chunks per group
#define SC    250         // scatter blocks (4 hist-chunks each)
#define SCE   12800       // edges per scatter block
#define CAP   3072        // per-bucket LDS edge capacity in sortdeg
#define NBLK  391         // ceil(N_/256)

// ---- A1: per-(chunk,bucket) histogram. countsA chunk-major [c][b].
__global__ void kA_hist(const int* __restrict__ col, int* __restrict__ countsA) {
    __shared__ int bins[BK];
    int c = blockIdx.x, t = threadIdx.x;
    for (int i = t; i < BK; i += 512) bins[i] = 0;
    __syncthreads();
    const int* cp = col + c * CSA;
    {
        int v0 = cp[t], v1 = cp[t + 512], v2 = cp[t + 1024], v3 = cp[t + 1536];
        atomicAdd(&bins[v0 >> 6], 1);
        atomicAdd(&bins[v1 >> 6], 1);
        atomicAdd(&bins[v2 >> 6], 1);
        atomicAdd(&bins[v3 >> 6], 1);
    }
    {
        int v0 = cp[t + 2048], v1 = cp[t + 2560];
        atomicAdd(&bins[v0 >> 6], 1);
        atomicAdd(&bins[v1 >> 6], 1);
    }
    if (t < 128) atomicAdd(&bins[cp[3072 + t] >> 6], 1);
    __syncthreads();
    int* outp = countsA + (size_t)c * BK;
    for (int i = t; i < BK; i += 512) outp[i] = bins[i];
}

// ---- A2a: within-group exclusive prefix across chunks.
__global__ void kA_scan1(int* __restrict__ countsA, int* __restrict__ grptot) {
    int tid = blockIdx.x * 256 + threadIdx.x;   // GG*BK = 20480 threads
    if (tid >= GG * BK) return;
    int g = tid >> 11;                          // / BK
    int b = tid & (BK - 1);
    int c0 = g * GCH;
    int run = 0;
    #pragma unroll 4
    for (int k = 0; k < GCH; k++) {
        size_t idx = (size_t)(c0 + k) * BK + b;
        int v = countsA[idx];
        countsA[idx] = run;
        run += v;
    }
    grptot[g * BK + b] = run;
}

// ---- A2b (one block): scan grptot across groups, bucket-base scan, fold.
__global__ void kA_scan2B(int* __restrict__ grptot, int* __restrict__ baseB) {
    __shared__ int sm[1024];
    int t = threadIdx.x;
    int tot0, tot1;
    {
        int b = 2 * t, run = 0;
        #pragma unroll
        for (int g = 0; g < GG; g++) {
            int idx = g * BK + b;
            int v = grptot[idx];
            grptot[idx] = run;
            run += v;
        }
        tot0 = run;
    }
    {
        int b = 2 * t + 1, run = 0;
        #pragma unroll
        for (int g = 0; g < GG; g++) {
            int idx = g * BK + b;
            int v = grptot[idx];
            grptot[idx] = run;
            run += v;
        }
        tot1 = run;
    }
    int pair = tot0 + tot1;
    sm[t] = pair;
    __syncthreads();
    for (int off = 1; off < 1024; off <<= 1) {
        int add = (t >= off) ? sm[t - off] : 0;
        __syncthreads();
        sm[t] += add;
        __syncthreads();
    }
    int excl = sm[t] - pair;
    baseB[2 * t]     = excl;
    baseB[2 * t + 1] = excl + tot0;
    if (t == 1023) baseB[BK] = sm[1023];
    #pragma unroll
    for (int g = 0; g < GG; g++) {
        grptot[g * BK + 2 * t]     += excl;
        grptot[g * BK + 2 * t + 1] += excl + tot0;
    }
}

// ---- A3: LDS bucket-sort 12800 edges, then run-contiguous global writes.
__global__ __launch_bounds__(512)
void kA_scatter2(const int* __restrict__ row, const int* __restrict__ col,
                 const float* __restrict__ w,
                 const int* __restrict__ countsA, const int* __restrict__ grptot,
                 int2* __restrict__ brec) {
    __shared__ int  lh[BK];          // hist -> shift
    __shared__ int  lc_[BK];         // lbase -> bump cursor
    __shared__ int  part[512];
    __shared__ int2 srec[SCE];       // 102400 B
    __shared__ unsigned short sbid[SCE];
    int c = blockIdx.x, t = threadIdx.x;
    int c4 = 4 * c;                  // first hist-chunk
    int g = c / 25;                  // = (4c)/GCH with GCH=100
    int E0 = c * SCE;
    for (int i = t; i < BK; i += 512) lh[i] = 0;
    __syncthreads();
    const int* cp = col + E0;
    const int* rp = row + E0;
    const float* wp = w + E0;
    // pass 1: local hist (25 iters)
    #pragma unroll 5
    for (int i = t; i < SCE; i += 512) atomicAdd(&lh[cp[i] >> 6], 1);
    __syncthreads();
    // local exclusive scan over 2048 bins (4 per thread + block scan)
    int b0 = t * 4;
    int h0 = lh[b0], h1 = lh[b0 + 1], h2 = lh[b0 + 2], h3 = lh[b0 + 3];
    int tot = h0 + h1 + h2 + h3;
    part[t] = tot;
    __syncthreads();
    for (int off = 1; off < 512; off <<= 1) {
        int add = (t >= off) ? part[t - off] : 0;
        __syncthreads();
        part[t] += add;
        __syncthreads();
    }
    int excl = part[t] - tot;
    lc_[b0]     = excl;
    lc_[b0 + 1] = excl + h0;
    lc_[b0 + 2] = excl + h0 + h1;
    lc_[b0 + 3] = excl + h0 + h1 + h2;
    __syncthreads();
    // shift[b] = global base for this block's bucket-b run - lbase[b]
    const int* gA = countsA + (size_t)c4 * BK;
    const int* gO = grptot + g * BK;
    for (int i = t; i < BK; i += 512) lh[i] = gO[i] + gA[i] - lc_[i];
    __syncthreads();
    // pass 2: stage records into LDS in bucket-sorted order
    #pragma unroll 5
    for (int i = t; i < SCE; i += 512) {
        int v = cp[i];
        int b = v >> 6;
        int lp = atomicAdd(&lc_[b], 1);
        srec[lp] = make_int2(rp[i] | ((v & 63) << 17), __float_as_int(wp[i]));
        sbid[lp] = (unsigned short)b;
    }
    __syncthreads();
    // pass 3: run-contiguous write-out: dst = shift[b] + j
    #pragma unroll 5
    for (int j = t; j < SCE; j += 512) {
        int b = sbid[j];
        brec[lh[b] + j] = srec[j];
    }
}

// ---- B-sort: per-bucket counting sort -> per-node CSR + deg + dinv + xw.
__global__ void kB_sortdeg(const int* __restrict__ baseB, int2* __restrict__ brec,
                           const float* __restrict__ x,
                           float* __restrict__ dinv, float* __restrict__ xw,
                           int* __restrict__ nodeptr) {
    __shared__ int2  raw[CAP];
    __shared__ int   h[4 * 64];
    __shared__ float degw[4 * 64];
    __shared__ int   nb[65];
    int b = blockIdx.x, t = threadIdx.x;
    int wid = t >> 6;
    int st = baseB[b];
    int cnt = baseB[b + 1] - st;
    if (cnt > CAP) cnt = CAP;
    h[t] = 0;
    degw[t] = 0.0f;
    __syncthreads();
    int i = t;
    for (; i + 768 < cnt; i += 1024) {
        int2 q0 = brec[st + i],       q1 = brec[st + i + 256];
        int2 q2 = brec[st + i + 512], q3 = brec[st + i + 768];
        raw[i] = q0; raw[i + 256] = q1; raw[i + 512] = q2; raw[i + 768] = q3;
        int hb = wid << 6;
        atomicAdd(&h[hb + (q0.x >> 17)], 1);
        atomicAdd(&h[hb + (q1.x >> 17)], 1);
        atomicAdd(&h[hb + (q2.x >> 17)], 1);
        atomicAdd(&h[hb + (q3.x >> 17)], 1);
        atomicAdd(&degw[hb + (q0.x >> 17)], __int_as_float(q0.y));
        atomicAdd(&degw[hb + (q1.x >> 17)], __int_as_float(q1.y));
        atomicAdd(&degw[hb + (q2.x >> 17)], __int_as_float(q2.y));
        atomicAdd(&degw[hb + (q3.x >> 17)], __int_as_float(q3.y));
    }
    for (; i < cnt; i += 256) {
        int2 q = brec[st + i];
        raw[i] = q;
        atomicAdd(&h[(wid << 6) + (q.x >> 17)], 1);
        atomicAdd(&degw[(wid << 6) + (q.x >> 17)], __int_as_float(q.y));
    }
    __syncthreads();
    if (t < 64) {
        int off = 0;
        #pragma unroll
        for (int w2 = 0; w2 < 4; w2++) {
            int cc = h[(w2 << 6) + t];
            h[(w2 << 6) + t] = off;
            off += cc;
        }
        int val = off;
        #pragma unroll
        for (int d = 1; d < 64; d <<= 1) {
            int u = __shfl_up(val, d);
            if (t >= d) val += u;
        }
        nb[t] = val - off;
        if (t == 63) nb[64] = val;
    }
    __syncthreads();
    if (t < 64) {
        int e2 = nb[t];
        #pragma unroll
        for (int w2 = 0; w2 < 4; w2++) h[(w2 << 6) + t] += e2;
    }
    __syncthreads();
    for (int j = t; j < cnt; j += 256) {
        int2 q = raw[j];
        int lc = q.x >> 17;
        int pos = atomicAdd(&h[(wid << 6) + lc], 1);
        brec[st + pos] = make_int2(q.x & 0x1FFFF, q.y);
    }
    if (t < 64) {
        int n = (b << 6) + t;
        if (n < N_) {
            float d = degw[t] + degw[64 + t] + degw[128 + t] + degw[192 + t];
            float di = rsqrtf(d + 1.0f);
            dinv[n] = di;
            nodeptr[n] = st + nb[t];
            const float4* xi = (const float4*)(x + (size_t)n * 8);
            float4 xa = xi[0], xb = xi[1];
            float4* o = (float4*)(xw + (size_t)n * 8);
            o[0] = make_float4(di * xa.x, di * xa.y, di * xa.z, di * xa.w);
            o[1] = make_float4(di * xb.x, di * xb.y, di * xb.z, di * xb.w);
        }
        if (b == NBUCK - 1 && t == 0) nodeptr[N_] = E_;
    }
}

// ---- B2: 2 threads/node register aggregation + split MLP. Zero atomics.
__global__ void kB2_node(const int* __restrict__ nodeptr, const int2* __restrict__ srec,
                         const float* __restrict__ dinv,
                         const float* __restrict__ xw,
                         const float* __restrict__ W1,
                         const float* __restrict__ b1,
                         const float* __restrict__ W2,
                         float* __restrict__ tv) {
    __shared__ float sW1[8 * 64];
    __shared__ float sb1[64];
    __shared__ float sW2[64];
    int t = threadIdx.x;                  // 512 threads
    sW1[t] = W1[t];
    if (t < 64) { sb1[t] = b1[t]; sW2[t] = W2[t]; }
    __syncthreads();
    int n = blockIdx.x * 256 + (t >> 1);
    int half = t & 1;
    if (n >= N_) return;
    int st = nodeptr[n], en = nodeptr[n + 1];
    const float4* xw4 = (const float4*)xw;
    float a[8];
    if (half == 0) {
        float4 s0 = xw4[2 * n], s1 = xw4[2 * n + 1];
        a[0] = s0.x; a[1] = s0.y; a[2] = s0.z; a[3] = s0.w;
        a[4] = s1.x; a[5] = s1.y; a[6] = s1.z; a[7] = s1.w;
    } else {
        #pragma unroll
        for (int k = 0; k < 8; k++) a[k] = 0.0f;
    }
    int e = st + half;
    for (; e + 2 < en; e += 4) {
        int2 q0 = srec[e], q1 = srec[e + 2];
        float4 f0a = xw4[2 * q0.x], f0b = xw4[2 * q0.x + 1];
        float4 f1a = xw4[2 * q1.x], f1b = xw4[2 * q1.x + 1];
        float w0 = __int_as_float(q0.y), w1 = __int_as_float(q1.y);
        a[0] = fmaf(w0, f0a.x, a[0]); a[1] = fmaf(w0, f0a.y, a[1]);
        a[2] = fmaf(w0, f0a.z, a[2]); a[3] = fmaf(w0, f0a.w, a[3]);
        a[4] = fmaf(w0, f0b.x, a[4]); a[5] = fmaf(w0, f0b.y, a[5]);
        a[6] = fmaf(w0, f0b.z, a[6]); a[7] = fmaf(w0, f0b.w, a[7]);
        a[0] = fmaf(w1, f1a.x, a[0]); a[1] = fmaf(w1, f1a.y, a[1]);
        a[2] = fmaf(w1, f1a.z, a[2]); a[3] = fmaf(w1, f1a.w, a[3]);
        a[4] = fmaf(w1, f1b.x, a[4]); a[5] = fmaf(w1, f1b.y, a[5]);
        a[6] = fmaf(w1, f1b.z, a[6]); a[7] = fmaf(w1, f1b.w, a[7]);
    }
    if (e < en) {
        int2 q = srec[e];
        float4 fa = xw4[2 * q.x], fb = xw4[2 * q.x + 1];
        float w0 = __int_as_float(q.y);
        a[0] = fmaf(w0, fa.x, a[0]); a[1] = fmaf(w0, fa.y, a[1]);
        a[2] = fmaf(w0, fa.z, a[2]); a[3] = fmaf(w0, fa.w, a[3]);
        a[4] = fmaf(w0, fb.x, a[4]); a[5] = fmaf(w0, fb.y, a[5]);
        a[6] = fmaf(w0, fb.z, a[6]); a[7] = fmaf(w0, fb.w, a[7]);
    }
    #pragma unroll
    for (int k = 0; k < 8; k++) a[k] += __shfl_xor(a[k], 1);
    float di = dinv[n];
    #pragma unroll
    for (int k = 0; k < 8; k++) a[k] *= di;
    float sv = 0.0f;
    int jb = half << 5;
    #pragma unroll
    for (int j = 0; j < 32; j++) {
        int jj = jb + j;
        float h = sb1[jj];
        #pragma unroll
        for (int k = 0; k < 8; k++) h = fmaf(a[k], sW1[k * 64 + jj], h);
        sv = fmaf(fmaxf(h, 0.0f), sW2[jj], sv);
    }
    sv += __shfl_xor(sv, 1);
    if (half == 0) tv[n] = di * sv;
}

// ---- B3: 2 threads/node layer-2.
__global__ void kB3_node(const int* __restrict__ nodeptr, const int2* __restrict__ srec,
                         const float* __restrict__ dinv,
                         const float* __restrict__ tv,
                         const float* __restrict__ b2,
                         float* __restrict__ out) {
    int t = threadIdx.x;                  // 512 threads
    int n = blockIdx.x * 256 + (t >> 1);
    int half = t & 1;
    if (n >= N_) return;
    int st = nodeptr[n], en = nodeptr[n + 1];
    float acc = (half == 0) ? tv[n] : 0.0f;
    int e = st + half;
    for (; e + 6 < en; e += 8) {
        int2 q0 = srec[e], q1 = srec[e + 2], q2 = srec[e + 4], q3 = srec[e + 6];
        float t0 = tv[q0.x], t1 = tv[q1.x], t2 = tv[q2.x], t3 = tv[q3.x];
        acc = fmaf(__int_as_float(q0.y), t0, acc);
        acc = fmaf(__int_as_float(q1.y), t1, acc);
        acc = fmaf(__int_as_float(q2.y), t2, acc);
        acc = fmaf(__int_as_float(q3.y), t3, acc);
    }
    for (; e < en; e += 2) {
        int2 q = srec[e];
        acc = fmaf(__int_as_float(q.y), tv[q.x], acc);
    }
    acc += __shfl_xor(acc, 1);
    if (half == 0) out[n] = b2[0] + dinv[n] * acc;
}

extern "C" void kernel_launch(void* const* d_in, const int* in_sizes, int n_in,
                              void* d_out, int out_size, void* d_ws, size_t ws_size,
                              hipStream_t stream) {
    const float* x  = (const float*)d_in[0];
    const int*   ei = (const int*)d_in[1];    // [2, E] int32
    const float* w  = (const float*)d_in[2];
    const float* W1 = (const float*)d_in[3];
    const float* b1 = (const float*)d_in[4];
    const float* W2 = (const float*)d_in[5];
    const float* b2 = (const float*)d_in[6];
    float* out = (float*)d_out;

    const int* row = ei;
    const int* col = ei + E_;

    // ws (ints): countsA[CA*BK]=2048000 | grptot[GG*BK]=20480 |
    //   baseB[2049 pad 2560] | nodeptr[100352] | dinv[N] | xw[8N] | tv[N] |
    //   brec[E] int2
    int*   wsI     = (int*)d_ws;
    int*   countsA = wsI;
    int*   grptot  = wsI + (size_t)CA * BK;          // 2048000
    int*   baseB   = grptot + GG * BK;               // +20480
    int*   nodeptr = baseB + 2560;
    float* dinv    = (float*)(nodeptr + 100352);
    float* xw      = dinv + N_;
    float* tv      = xw + (size_t)8 * N_;
    int2*  brec    = (int2*)(tv + N_);

    kA_hist    <<<CA, 512, 0, stream>>>(col, countsA);
    kA_scan1   <<<(GG * BK + 255) / 256, 256, 0, stream>>>(countsA, grptot);
    kA_scan2B  <<<1, 1024, 0, stream>>>(grptot, baseB);
    kA_scatter2<<<SC, 512, 0, stream>>>(row, col, w, countsA, grptot, brec);
    kB_sortdeg <<<NBUCK, 256, 0, stream>>>(baseB, brec, x, dinv, xw, nodeptr);
    kB2_node   <<<NBLK, 512, 0, stream>>>(nodeptr, brec, dinv, xw, W1, b1, W2, tv);
    kB3_node   <<<NBLK, 512, 0, stream>>>(nodeptr, brec, dinv, tv, b2, out);
}

// Round 13
// 227.711 us; speedup vs baseline: 1.0936x; 1.0404x over previous
//
#include <hip/hip_runtime.h>

// GCN 2-layer: N=100000, E=3200000, IN=8, HID=64, OUT=1.
// Round 13: R12 pipeline + 4-threads/node kB2/kB3.
//  R12's kB2_node (44us): gather-latency bound at 22% occupancy (391 blocks
//  = 3128 waves of 8192 slots) with ~2 gathers in flight/thread. Now 4
//  thr/node -> 782 blocks = 6256 waves (76% cap) and 2-edge unroll/lane.
//  Scatter2 (run-coalesced stores, R12 win) unchanged.

#define N_    100000
#define E_    3200000
#define BK    2048        // buckets = col >> 6 (64 nodes/bucket)
#define NBUCK 1563        // ceil(N_/64)
#define CA    1000        // hist chunks
#define CSA   3200        // E_/CA
#define GG    10          // chunk groups (GCH multiple of 4!)
#define GCH   100         // chunks per group
#define SC    250         // scatter blocks (4 hist-chunks each)
#define SCE   12800       // edges per scatter block
#define CAP   3072        // per-bucket LDS edge capacity in sortdeg
#define NBLK4 782         // ceil(N_/128)

// ---- A1: per-(chunk,bucket) histogram. countsA chunk-major [c][b].
__global__ void kA_hist(const int* __restrict__ col, int* __restrict__ countsA) {
    __shared__ int bins[BK];
    int c = blockIdx.x, t = threadIdx.x;
    for (int i = t; i < BK; i += 512) bins[i] = 0;
    __syncthreads();
    const int* cp = col + c * CSA;
    {
        int v0 = cp[t], v1 = cp[t + 512], v2 = cp[t + 1024], v3 = cp[t + 1536];
        atomicAdd(&bins[v0 >> 6], 1);
        atomicAdd(&bins[v1 >> 6], 1);
        atomicAdd(&bins[v2 >> 6], 1);
        atomicAdd(&bins[v3 >> 6], 1);
    }
    {
        int v0 = cp[t + 2048], v1 = cp[t + 2560];
        atomicAdd(&bins[v0 >> 6], 1);
        atomicAdd(&bins[v1 >> 6], 1);
    }
    if (t < 128) atomicAdd(&bins[cp[3072 + t] >> 6], 1);
    __syncthreads();
    int* outp = countsA + (size_t)c * BK;
    for (int i = t; i < BK; i += 512) outp[i] = bins[i];
}

// ---- A2a: within-group exclusive prefix across chunks.
__global__ void kA_scan1(int* __restrict__ countsA, int* __restrict__ grptot) {
    int tid = blockIdx.x * 256 + threadIdx.x;   // GG*BK = 20480 threads
    if (tid >= GG * BK) return;
    int g = tid >> 11;
    int b = tid & (BK - 1);
    int c0 = g * GCH;
    int run = 0;
    #pragma unroll 4
    for (int k = 0; k < GCH; k++) {
        size_t idx = (size_t)(c0 + k) * BK + b;
        int v = countsA[idx];
        countsA[idx] = run;
        run += v;
    }
    grptot[g * BK + b] = run;
}

// ---- A2b (one block): scan grptot across groups, bucket-base scan, fold.
__global__ void kA_scan2B(int* __restrict__ grptot, int* __restrict__ baseB) {
    __shared__ int sm[1024];
    int t = threadIdx.x;
    int tot0, tot1;
    {
        int b = 2 * t, run = 0;
        #pragma unroll
        for (int g = 0; g < GG; g++) {
            int idx = g * BK + b;
            int v = grptot[idx];
            grptot[idx] = run;
            run += v;
        }
        tot0 = run;
    }
    {
        int b = 2 * t + 1, run = 0;
        #pragma unroll
        for (int g = 0; g < GG; g++) {
            int idx = g * BK + b;
            int v = grptot[idx];
            grptot[idx] = run;
            run += v;
        }
        tot1 = run;
    }
    int pair = tot0 + tot1;
    sm[t] = pair;
    __syncthreads();
    for (int off = 1; off < 1024; off <<= 1) {
        int add = (t >= off) ? sm[t - off] : 0;
        __syncthreads();
        sm[t] += add;
        __syncthreads();
    }
    int excl = sm[t] - pair;
    baseB[2 * t]     = excl;
    baseB[2 * t + 1] = excl + tot0;
    if (t == 1023) baseB[BK] = sm[1023];
    #pragma unroll
    for (int g = 0; g < GG; g++) {
        grptot[g * BK + 2 * t]     += excl;
        grptot[g * BK + 2 * t + 1] += excl + tot0;
    }
}

// ---- A3: LDS bucket-sort 12800 edges, then run-contiguous global writes.
__global__ __launch_bounds__(512)
void kA_scatter2(const int* __restrict__ row, const int* __restrict__ col,
                 const float* __restrict__ w,
                 const int* __restrict__ countsA, const int* __restrict__ grptot,
                 int2* __restrict__ brec) {
    __shared__ int  lh[BK];
    __shared__ int  lc_[BK];
    __shared__ int  part[512];
    __shared__ int2 srec[SCE];
    __shared__ unsigned short sbid[SCE];
    int c = blockIdx.x, t = threadIdx.x;
    int c4 = 4 * c;
    int g = c / 25;
    int E0 = c * SCE;
    for (int i = t; i < BK; i += 512) lh[i] = 0;
    __syncthreads();
    const int* cp = col + E0;
    const int* rp = row + E0;
    const float* wp = w + E0;
    #pragma unroll 5
    for (int i = t; i < SCE; i += 512) atomicAdd(&lh[cp[i] >> 6], 1);
    __syncthreads();
    int b0 = t * 4;
    int h0 = lh[b0], h1 = lh[b0 + 1], h2 = lh[b0 + 2], h3 = lh[b0 + 3];
    int tot = h0 + h1 + h2 + h3;
    part[t] = tot;
    __syncthreads();
    for (int off = 1; off < 512; off <<= 1) {
        int add = (t >= off) ? part[t - off] : 0;
        __syncthreads();
        part[t] += add;
        __syncthreads();
    }
    int excl = part[t] - tot;
    lc_[b0]     = excl;
    lc_[b0 + 1] = excl + h0;
    lc_[b0 + 2] = excl + h0 + h1;
    lc_[b0 + 3] = excl + h0 + h1 + h2;
    __syncthreads();
    const int* gA = countsA + (size_t)c4 * BK;
    const int* gO = grptot + g * BK;
    for (int i = t; i < BK; i += 512) lh[i] = gO[i] + gA[i] - lc_[i];
    __syncthreads();
    #pragma unroll 5
    for (int i = t; i < SCE; i += 512) {
        int v = cp[i];
        int b = v >> 6;
        int lp = atomicAdd(&lc_[b], 1);
        srec[lp] = make_int2(rp[i] | ((v & 63) << 17), __float_as_int(wp[i]));
        sbid[lp] = (unsigned short)b;
    }
    __syncthreads();
    #pragma unroll 5
    for (int j = t; j < SCE; j += 512) {
        int b = sbid[j];
        brec[lh[b] + j] = srec[j];
    }
}

// ---- B-sort: per-bucket counting sort -> per-node CSR + deg + dinv + xw.
__global__ void kB_sortdeg(const int* __restrict__ baseB, int2* __restrict__ brec,
                           const float* __restrict__ x,
                           float* __restrict__ dinv, float* __restrict__ xw,
                           int* __restrict__ nodeptr) {
    __shared__ int2  raw[CAP];
    __shared__ int   h[4 * 64];
    __shared__ float degw[4 * 64];
    __shared__ int   nb[65];
    int b = blockIdx.x, t = threadIdx.x;
    int wid = t >> 6;
    int st = baseB[b];
    int cnt = baseB[b + 1] - st;
    if (cnt > CAP) cnt = CAP;
    h[t] = 0;
    degw[t] = 0.0f;
    __syncthreads();
    int i = t;
    for (; i + 768 < cnt; i += 1024) {
        int2 q0 = brec[st + i],       q1 = brec[st + i + 256];
        int2 q2 = brec[st + i + 512], q3 = brec[st + i + 768];
        raw[i] = q0; raw[i + 256] = q1; raw[i + 512] = q2; raw[i + 768] = q3;
        int hb = wid << 6;
        atomicAdd(&h[hb + (q0.x >> 17)], 1);
        atomicAdd(&h[hb + (q1.x >> 17)], 1);
        atomicAdd(&h[hb + (q2.x >> 17)], 1);
        atomicAdd(&h[hb + (q3.x >> 17)], 1);
        atomicAdd(&degw[hb + (q0.x >> 17)], __int_as_float(q0.y));
        atomicAdd(&degw[hb + (q1.x >> 17)], __int_as_float(q1.y));
        atomicAdd(&degw[hb + (q2.x >> 17)], __int_as_float(q2.y));
        atomicAdd(&degw[hb + (q3.x >> 17)], __int_as_float(q3.y));
    }
    for (; i < cnt; i += 256) {
        int2 q = brec[st + i];
        raw[i] = q;
        atomicAdd(&h[(wid << 6) + (q.x >> 17)], 1);
        atomicAdd(&degw[(wid << 6) + (q.x >> 17)], __int_as_float(q.y));
    }
    __syncthreads();
    if (t < 64) {
        int off = 0;
        #pragma unroll
        for (int w2 = 0; w2 < 4; w2++) {
            int cc = h[(w2 << 6) + t];
            h[(w2 << 6) + t] = off;
            off += cc;
        }
        int val = off;
        #pragma unroll
        for (int d = 1; d < 64; d <<= 1) {
            int u = __shfl_up(val, d);
            if (t >= d) val += u;
        }
        nb[t] = val - off;
        if (t == 63) nb[64] = val;
    }
    __syncthreads();
    if (t < 64) {
        int e2 = nb[t];
        #pragma unroll
        for (int w2 = 0; w2 < 4; w2++) h[(w2 << 6) + t] += e2;
    }
    __syncthreads();
    for (int j = t; j < cnt; j += 256) {
        int2 q = raw[j];
        int lc = q.x >> 17;
        int pos = atomicAdd(&h[(wid << 6) + lc], 1);
        brec[st + pos] = make_int2(q.x & 0x1FFFF, q.y);
    }
    if (t < 64) {
        int n = (b << 6) + t;
        if (n < N_) {
            float d = degw[t] + degw[64 + t] + degw[128 + t] + degw[192 + t];
            float di = rsqrtf(d + 1.0f);
            dinv[n] = di;
            nodeptr[n] = st + nb[t];
            const float4* xi = (const float4*)(x + (size_t)n * 8);
            float4 xa = xi[0], xb = xi[1];
            float4* o = (float4*)(xw + (size_t)n * 8);
            o[0] = make_float4(di * xa.x, di * xa.y, di * xa.z, di * xa.w);
            o[1] = make_float4(di * xb.x, di * xb.y, di * xb.z, di * xb.w);
        }
        if (b == NBUCK - 1 && t == 0) nodeptr[N_] = E_;
    }
}

// ---- B2: 4 threads/node register aggregation + split MLP. Zero atomics.
__global__ __launch_bounds__(512)
void kB2_node(const int* __restrict__ nodeptr, const int2* __restrict__ srec,
              const float* __restrict__ dinv,
              const float* __restrict__ xw,
              const float* __restrict__ W1,
              const float* __restrict__ b1,
              const float* __restrict__ W2,
              float* __restrict__ tv) {
    __shared__ float sW1[8 * 64];
    __shared__ float sb1[64];
    __shared__ float sW2[64];
    int t = threadIdx.x;                  // 512 threads, 128 nodes/block
    sW1[t] = W1[t];
    if (t < 64) { sb1[t] = b1[t]; sW2[t] = W2[t]; }
    __syncthreads();
    int n = blockIdx.x * 128 + (t >> 2);
    int q = t & 3;
    if (n >= N_) return;
    int st = nodeptr[n], en = nodeptr[n + 1];
    const float4* xw4 = (const float4*)xw;
    float a[8];
    if (q == 0) {
        float4 s0 = xw4[2 * n], s1 = xw4[2 * n + 1];
        a[0] = s0.x; a[1] = s0.y; a[2] = s0.z; a[3] = s0.w;
        a[4] = s1.x; a[5] = s1.y; a[6] = s1.z; a[7] = s1.w;
    } else {
        #pragma unroll
        for (int k = 0; k < 8; k++) a[k] = 0.0f;
    }
    int e = st + q;
    for (; e + 4 < en; e += 8) {          // 2 edges per iter (stride 4)
        int2 q0 = srec[e], q1 = srec[e + 4];
        float4 f0a = xw4[2 * q0.x], f0b = xw4[2 * q0.x + 1];
        float4 f1a = xw4[2 * q1.x], f1b = xw4[2 * q1.x + 1];
        float w0 = __int_as_float(q0.y), w1 = __int_as_float(q1.y);
        a[0] = fmaf(w0, f0a.x, a[0]); a[1] = fmaf(w0, f0a.y, a[1]);
        a[2] = fmaf(w0, f0a.z, a[2]); a[3] = fmaf(w0, f0a.w, a[3]);
        a[4] = fmaf(w0, f0b.x, a[4]); a[5] = fmaf(w0, f0b.y, a[5]);
        a[6] = fmaf(w0, f0b.z, a[6]); a[7] = fmaf(w0, f0b.w, a[7]);
        a[0] = fmaf(w1, f1a.x, a[0]); a[1] = fmaf(w1, f1a.y, a[1]);
        a[2] = fmaf(w1, f1a.z, a[2]); a[3] = fmaf(w1, f1a.w, a[3]);
        a[4] = fmaf(w1, f1b.x, a[4]); a[5] = fmaf(w1, f1b.y, a[5]);
        a[6] = fmaf(w1, f1b.z, a[6]); a[7] = fmaf(w1, f1b.w, a[7]);
    }
    if (e < en) {
        int2 qq = srec[e];
        float4 fa = xw4[2 * qq.x], fb = xw4[2 * qq.x + 1];
        float w0 = __int_as_float(qq.y);
        a[0] = fmaf(w0, fa.x, a[0]); a[1] = fmaf(w0, fa.y, a[1]);
        a[2] = fmaf(w0, fa.z, a[2]); a[3] = fmaf(w0, fa.w, a[3]);
        a[4] = fmaf(w0, fb.x, a[4]); a[5] = fmaf(w0, fb.y, a[5]);
        a[6] = fmaf(w0, fb.z, a[6]); a[7] = fmaf(w0, fb.w, a[7]);
    }
    // reduce a[] across the 4 lanes of this node
    #pragma unroll
    for (int k = 0; k < 8; k++) {
        a[k] += __shfl_xor(a[k], 1);
        a[k] += __shfl_xor(a[k], 2);
    }
    float di = dinv[n];
    #pragma unroll
    for (int k = 0; k < 8; k++) a[k] *= di;
    // split MLP: quarter q -> j = 16q .. 16q+15
    float sv = 0.0f;
    int jb = q << 4;
    #pragma unroll
    for (int j = 0; j < 16; j++) {
        int jj = jb + j;
        float h = sb1[jj];
        #pragma unroll
        for (int k = 0; k < 8; k++) h = fmaf(a[k], sW1[k * 64 + jj], h);
        sv = fmaf(fmaxf(h, 0.0f), sW2[jj], sv);
    }
    sv += __shfl_xor(sv, 1);
    sv += __shfl_xor(sv, 2);
    if (q == 0) tv[n] = di * sv;
}

// ---- B3: 4 threads/node layer-2.
__global__ __launch_bounds__(512)
void kB3_node(const int* __restrict__ nodeptr, const int2* __restrict__ srec,
              const float* __restrict__ dinv,
              const float* __restrict__ tv,
              const float* __restrict__ b2,
              float* __restrict__ out) {
    int t = threadIdx.x;                  // 512 threads, 128 nodes/block
    int n = blockIdx.x * 128 + (t >> 2);
    int q = t & 3;
    if (n >= N_) return;
    int st = nodeptr[n], en = nodeptr[n + 1];
    float acc = (q == 0) ? tv[n] : 0.0f;
    int e = st + q;
    for (; e + 4 < en; e += 8) {          // 2 edges per iter (stride 4)
        int2 q0 = srec[e], q1 = srec[e + 4];
        float t0 = tv[q0.x], t1 = tv[q1.x];
        acc = fmaf(__int_as_float(q0.y), t0, acc);
        acc = fmaf(__int_as_float(q1.y), t1, acc);
    }
    if (e < en) {
        int2 qq = srec[e];
        acc = fmaf(__int_as_float(qq.y), tv[qq.x], acc);
    }
    acc += __shfl_xor(acc, 1);
    acc += __shfl_xor(acc, 2);
    if (q == 0) out[n] = b2[0] + dinv[n] * acc;
}

extern "C" void kernel_launch(void* const* d_in, const int* in_sizes, int n_in,
                              void* d_out, int out_size, void* d_ws, size_t ws_size,
                              hipStream_t stream) {
    const float* x  = (const float*)d_in[0];
    const int*   ei = (const int*)d_in[1];    // [2, E] int32
    const float* w  = (const float*)d_in[2];
    const float* W1 = (const float*)d_in[3];
    const float* b1 = (const float*)d_in[4];
    const float* W2 = (const float*)d_in[5];
    const float* b2 = (const float*)d_in[6];
    float* out = (float*)d_out;

    const int* row = ei;
    const int* col = ei + E_;

    // ws (ints): countsA[CA*BK]=2048000 | grptot[GG*BK]=20480 |
    //   baseB[2049 pad 2560] | nodeptr[100352] | dinv[N] | xw[8N] | tv[N] |
    //   brec[E] int2
    int*   wsI     = (int*)d_ws;
    int*   countsA = wsI;
    int*   grptot  = wsI + (size_t)CA * BK;          // 2048000
    int*   baseB   = grptot + GG * BK;               // +20480
    int*   nodeptr = baseB + 2560;
    float* dinv    = (float*)(nodeptr + 100352);
    float* xw      = dinv + N_;
    float* tv      = xw + (size_t)8 * N_;
    int2*  brec    = (int2*)(tv + N_);

    kA_hist    <<<CA, 512, 0, stream>>>(col, countsA);
    kA_scan1   <<<(GG * BK + 255) / 256, 256, 0, stream>>>(countsA, grptot);
    kA_scan2B  <<<1, 1024, 0, stream>>>(grptot, baseB);
    kA_scatter2<<<SC, 512, 0, stream>>>(row, col, w, countsA, grptot, brec);
    kB_sortdeg <<<NBUCK, 256, 0, stream>>>(baseB, brec, x, dinv, xw, nodeptr);
    kB2_node   <<<NBLK4, 512, 0, stream>>>(nodeptr, brec, dinv, xw, W1, b1, W2, tv);
    kB3_node   <<<NBLK4, 512, 0, stream>>>(nodeptr, brec, dinv, tv, b2, out);
}

// Round 14
// 213.789 us; speedup vs baseline: 1.1648x; 1.0651x over previous
//
#include <hip/hip_runtime.h>

// GCN 2-layer: N=100000, E=3200000, IN=8, HID=64, OUT=1.
// Round 14: scatter occupancy + dedup.
//  R13's kA_scatter2 (43us): 143KB LDS -> 1 block/CU, 11.7% occupancy, and
//  its pass-1 local hist duplicated kA_hist's work. Now: 6400-edge blocks
//  (SCE=CSA=6400, 500 blocks), LDS 80KB (part aliased into sbid) -> 2
//  blocks/CU; scatter loads its bins from countsA (raw) + countsP (prefix)
//  instead of re-histogramming. Everything else unchanged from R13.

#define N_    100000
#define E_    3200000
#define BK    2048        // buckets = col >> 6 (64 nodes/bucket)
#define NBUCK 1563        // ceil(N_/64)
#define CA    500         // chunks (= scatter blocks)
#define CSA   6400        // E_/CA
#define GG    10          // chunk groups
#define GCH   50          // chunks per group
#define SCE   6400        // edges per scatter block
#define CAP   3072        // per-bucket LDS edge capacity in sortdeg
#define NBLK4 782         // ceil(N_/128)

// ---- A1: per-(chunk,bucket) histogram. countsA chunk-major [c][b], RAW.
__global__ void kA_hist(const int* __restrict__ col, int* __restrict__ countsA) {
    __shared__ int bins[BK];
    int c = blockIdx.x, t = threadIdx.x;
    for (int i = t; i < BK; i += 512) bins[i] = 0;
    __syncthreads();
    const int* cp = col + c * CSA;
    #pragma unroll
    for (int it = 0; it < 3; it++) {            // 3 x 4 x 512 = 6144
        int e = t + it * 2048;
        int v0 = cp[e], v1 = cp[e + 512], v2 = cp[e + 1024], v3 = cp[e + 1536];
        atomicAdd(&bins[v0 >> 6], 1);
        atomicAdd(&bins[v1 >> 6], 1);
        atomicAdd(&bins[v2 >> 6], 1);
        atomicAdd(&bins[v3 >> 6], 1);
    }
    if (t < 256) atomicAdd(&bins[cp[6144 + t] >> 6], 1);
    __syncthreads();
    int* outp = countsA + (size_t)c * BK;
    for (int i = t; i < BK; i += 512) outp[i] = bins[i];
}

// ---- A2a: within-group exclusive prefix across chunks (raw in, prefix out).
__global__ void kA_scan1(const int* __restrict__ countsA, int* __restrict__ countsP,
                         int* __restrict__ grptot) {
    int tid = blockIdx.x * 256 + threadIdx.x;   // GG*BK = 20480 threads
    if (tid >= GG * BK) return;
    int g = tid >> 11;
    int b = tid & (BK - 1);
    int c0 = g * GCH;
    int run = 0;
    #pragma unroll 5
    for (int k = 0; k < GCH; k++) {
        size_t idx = (size_t)(c0 + k) * BK + b;
        int v = countsA[idx];
        countsP[idx] = run;
        run += v;
    }
    grptot[g * BK + b] = run;
}

// ---- A2b (one block): scan grptot across groups, bucket-base scan, fold.
__global__ void kA_scan2B(int* __restrict__ grptot, int* __restrict__ baseB) {
    __shared__ int sm[1024];
    int t = threadIdx.x;
    int tot0, tot1;
    {
        int b = 2 * t, run = 0;
        #pragma unroll
        for (int g = 0; g < GG; g++) {
            int idx = g * BK + b;
            int v = grptot[idx];
            grptot[idx] = run;
            run += v;
        }
        tot0 = run;
    }
    {
        int b = 2 * t + 1, run = 0;
        #pragma unroll
        for (int g = 0; g < GG; g++) {
            int idx = g * BK + b;
            int v = grptot[idx];
            grptot[idx] = run;
            run += v;
        }
        tot1 = run;
    }
    int pair = tot0 + tot1;
    sm[t] = pair;
    __syncthreads();
    for (int off = 1; off < 1024; off <<= 1) {
        int add = (t >= off) ? sm[t - off] : 0;
        __syncthreads();
        sm[t] += add;
        __syncthreads();
    }
    int excl = sm[t] - pair;
    baseB[2 * t]     = excl;
    baseB[2 * t + 1] = excl + tot0;
    if (t == 1023) baseB[BK] = sm[1023];
    #pragma unroll
    for (int g = 0; g < GG; g++) {
        grptot[g * BK + 2 * t]     += excl;
        grptot[g * BK + 2 * t + 1] += excl + tot0;
    }
}

// ---- A3: LDS bucket-sort 6400 edges, run-contiguous global writes.
//   Bins come from countsA (raw) / countsP (prefix) — no local hist pass.
__global__ __launch_bounds__(512)
void kA_scatter2(const int* __restrict__ row, const int* __restrict__ col,
                 const float* __restrict__ w,
                 const int* __restrict__ countsA, const int* __restrict__ countsP,
                 const int* __restrict__ grptot,
                 int2* __restrict__ brec) {
    __shared__ int  lh[BK];                 // shift
    __shared__ int  lc_[BK];                // local base -> bump cursor
    __shared__ int2 srec[SCE];              // 51200 B
    __shared__ unsigned short sbid[SCE];    // 12800 B (scan scratch aliased)
    int* part = (int*)sbid;                 // 512 ints, used before pass 2
    int c = blockIdx.x, t = threadIdx.x;
    int g = c / GCH;
    int E0 = c * SCE;
    // load raw bins (int4/thread), local exclusive scan over 2048 bins
    const int4* rawp = (const int4*)(countsA + (size_t)c * BK);
    int4 hv = rawp[t];
    int tot = hv.x + hv.y + hv.z + hv.w;
    part[t] = tot;
    __syncthreads();
    for (int off = 1; off < 512; off <<= 1) {
        int add = (t >= off) ? part[t - off] : 0;
        __syncthreads();
        part[t] += add;
        __syncthreads();
    }
    int excl = part[t] - tot;
    int b0 = t * 4;
    lc_[b0]     = excl;
    lc_[b0 + 1] = excl + hv.x;
    lc_[b0 + 2] = excl + hv.x + hv.y;
    lc_[b0 + 3] = excl + hv.x + hv.y + hv.z;
    __syncthreads();
    // shift[b] = global run base - local base
    const int* gO = grptot + g * BK;
    const int* gP = countsP + (size_t)c * BK;
    for (int i = t; i < BK; i += 512) lh[i] = gO[i] + gP[i] - lc_[i];
    __syncthreads();
    // pass 2: stage records into LDS in bucket-sorted order
    const int* cp = col + E0;
    const int* rp = row + E0;
    const float* wp = w + E0;
    #pragma unroll 4
    for (int i = t; i < SCE; i += 512) {
        int v = cp[i];
        int b = v >> 6;
        int lp = atomicAdd(&lc_[b], 1);
        srec[lp] = make_int2(rp[i] | ((v & 63) << 17), __float_as_int(wp[i]));
        sbid[lp] = (unsigned short)b;
    }
    __syncthreads();
    // pass 3: run-contiguous write-out
    #pragma unroll 4
    for (int j = t; j < SCE; j += 512) {
        brec[lh[sbid[j]] + j] = srec[j];
    }
}

// ---- B-sort: per-bucket counting sort -> per-node CSR + deg + dinv + xw.
__global__ void kB_sortdeg(const int* __restrict__ baseB, int2* __restrict__ brec,
                           const float* __restrict__ x,
                           float* __restrict__ dinv, float* __restrict__ xw,
                           int* __restrict__ nodeptr) {
    __shared__ int2  raw[CAP];
    __shared__ int   h[4 * 64];
    __shared__ float degw[4 * 64];
    __shared__ int   nb[65];
    int b = blockIdx.x, t = threadIdx.x;
    int wid = t >> 6;
    int st = baseB[b];
    int cnt = baseB[b + 1] - st;
    if (cnt > CAP) cnt = CAP;
    h[t] = 0;
    degw[t] = 0.0f;
    __syncthreads();
    int i = t;
    for (; i + 768 < cnt; i += 1024) {
        int2 q0 = brec[st + i],       q1 = brec[st + i + 256];
        int2 q2 = brec[st + i + 512], q3 = brec[st + i + 768];
        raw[i] = q0; raw[i + 256] = q1; raw[i + 512] = q2; raw[i + 768] = q3;
        int hb = wid << 6;
        atomicAdd(&h[hb + (q0.x >> 17)], 1);
        atomicAdd(&h[hb + (q1.x >> 17)], 1);
        atomicAdd(&h[hb + (q2.x >> 17)], 1);
        atomicAdd(&h[hb + (q3.x >> 17)], 1);
        atomicAdd(&degw[hb + (q0.x >> 17)], __int_as_float(q0.y));
        atomicAdd(&degw[hb + (q1.x >> 17)], __int_as_float(q1.y));
        atomicAdd(&degw[hb + (q2.x >> 17)], __int_as_float(q2.y));
        atomicAdd(&degw[hb + (q3.x >> 17)], __int_as_float(q3.y));
    }
    for (; i < cnt; i += 256) {
        int2 q = brec[st + i];
        raw[i] = q;
        atomicAdd(&h[(wid << 6) + (q.x >> 17)], 1);
        atomicAdd(&degw[(wid << 6) + (q.x >> 17)], __int_as_float(q.y));
    }
    __syncthreads();
    if (t < 64) {
        int off = 0;
        #pragma unroll
        for (int w2 = 0; w2 < 4; w2++) {
            int cc = h[(w2 << 6) + t];
            h[(w2 << 6) + t] = off;
            off += cc;
        }
        int val = off;
        #pragma unroll
        for (int d = 1; d < 64; d <<= 1) {
            int u = __shfl_up(val, d);
            if (t >= d) val += u;
        }
        nb[t] = val - off;
        if (t == 63) nb[64] = val;
    }
    __syncthreads();
    if (t < 64) {
        int e2 = nb[t];
        #pragma unroll
        for (int w2 = 0; w2 < 4; w2++) h[(w2 << 6) + t] += e2;
    }
    __syncthreads();
    for (int j = t; j < cnt; j += 256) {
        int2 q = raw[j];
        int lc = q.x >> 17;
        int pos = atomicAdd(&h[(wid << 6) + lc], 1);
        brec[st + pos] = make_int2(q.x & 0x1FFFF, q.y);
    }
    if (t < 64) {
        int n = (b << 6) + t;
        if (n < N_) {
            float d = degw[t] + degw[64 + t] + degw[128 + t] + degw[192 + t];
            float di = rsqrtf(d + 1.0f);
            dinv[n] = di;
            nodeptr[n] = st + nb[t];
            const float4* xi = (const float4*)(x + (size_t)n * 8);
            float4 xa = xi[0], xb = xi[1];
            float4* o = (float4*)(xw + (size_t)n * 8);
            o[0] = make_float4(di * xa.x, di * xa.y, di * xa.z, di * xa.w);
            o[1] = make_float4(di * xb.x, di * xb.y, di * xb.z, di * xb.w);
        }
        if (b == NBUCK - 1 && t == 0) nodeptr[N_] = E_;
    }
}

// ---- B2: 4 threads/node register aggregation + split MLP. Zero atomics.
__global__ __launch_bounds__(512)
void kB2_node(const int* __restrict__ nodeptr, const int2* __restrict__ srec,
              const float* __restrict__ dinv,
              const float* __restrict__ xw,
              const float* __restrict__ W1,
              const float* __restrict__ b1,
              const float* __restrict__ W2,
              float* __restrict__ tv) {
    __shared__ float sW1[8 * 64];
    __shared__ float sb1[64];
    __shared__ float sW2[64];
    int t = threadIdx.x;                  // 512 threads, 128 nodes/block
    sW1[t] = W1[t];
    if (t < 64) { sb1[t] = b1[t]; sW2[t] = W2[t]; }
    __syncthreads();
    int n = blockIdx.x * 128 + (t >> 2);
    int q = t & 3;
    if (n >= N_) return;
    int st = nodeptr[n], en = nodeptr[n + 1];
    const float4* xw4 = (const float4*)xw;
    float a[8];
    if (q == 0) {
        float4 s0 = xw4[2 * n], s1 = xw4[2 * n + 1];
        a[0] = s0.x; a[1] = s0.y; a[2] = s0.z; a[3] = s0.w;
        a[4] = s1.x; a[5] = s1.y; a[6] = s1.z; a[7] = s1.w;
    } else {
        #pragma unroll
        for (int k = 0; k < 8; k++) a[k] = 0.0f;
    }
    int e = st + q;
    for (; e + 4 < en; e += 8) {
        int2 q0 = srec[e], q1 = srec[e + 4];
        float4 f0a = xw4[2 * q0.x], f0b = xw4[2 * q0.x + 1];
        float4 f1a = xw4[2 * q1.x], f1b = xw4[2 * q1.x + 1];
        float w0 = __int_as_float(q0.y), w1 = __int_as_float(q1.y);
        a[0] = fmaf(w0, f0a.x, a[0]); a[1] = fmaf(w0, f0a.y, a[1]);
        a[2] = fmaf(w0, f0a.z, a[2]); a[3] = fmaf(w0, f0a.w, a[3]);
        a[4] = fmaf(w0, f0b.x, a[4]); a[5] = fmaf(w0, f0b.y, a[5]);
        a[6] = fmaf(w0, f0b.z, a[6]); a[7] = fmaf(w0, f0b.w, a[7]);
        a[0] = fmaf(w1, f1a.x, a[0]); a[1] = fmaf(w1, f1a.y, a[1]);
        a[2] = fmaf(w1, f1a.z, a[2]); a[3] = fmaf(w1, f1a.w, a[3]);
        a[4] = fmaf(w1, f1b.x, a[4]); a[5] = fmaf(w1, f1b.y, a[5]);
        a[6] = fmaf(w1, f1b.z, a[6]); a[7] = fmaf(w1, f1b.w, a[7]);
    }
    if (e < en) {
        int2 qq = srec[e];
        float4 fa = xw4[2 * qq.x], fb = xw4[2 * qq.x + 1];
        float w0 = __int_as_float(qq.y);
        a[0] = fmaf(w0, fa.x, a[0]); a[1] = fmaf(w0, fa.y, a[1]);
        a[2] = fmaf(w0, fa.z, a[2]); a[3] = fmaf(w0, fa.w, a[3]);
        a[4] = fmaf(w0, fb.x, a[4]); a[5] = fmaf(w0, fb.y, a[5]);
        a[6] = fmaf(w0, fb.z, a[6]); a[7] = fmaf(w0, fb.w, a[7]);
    }
    #pragma unroll
    for (int k = 0; k < 8; k++) {
        a[k] += __shfl_xor(a[k], 1);
        a[k] += __shfl_xor(a[k], 2);
    }
    float di = dinv[n];
    #pragma unroll
    for (int k = 0; k < 8; k++) a[k] *= di;
    float sv = 0.0f;
    int jb = q << 4;
    #pragma unroll
    for (int j = 0; j < 16; j++) {
        int jj = jb + j;
        float h = sb1[jj];
        #pragma unroll
        for (int k = 0; k < 8; k++) h = fmaf(a[k], sW1[k * 64 + jj], h);
        sv = fmaf(fmaxf(h, 0.0f), sW2[jj], sv);
    }
    sv += __shfl_xor(sv, 1);
    sv += __shfl_xor(sv, 2);
    if (q == 0) tv[n] = di * sv;
}

// ---- B3: 4 threads/node layer-2.
__global__ __launch_bounds__(512)
void kB3_node(const int* __restrict__ nodeptr, const int2* __restrict__ srec,
              const float* __restrict__ dinv,
              const float* __restrict__ tv,
              const float* __restrict__ b2,
              float* __restrict__ out) {
    int t = threadIdx.x;
    int n = blockIdx.x * 128 + (t >> 2);
    int q = t & 3;
    if (n >= N_) return;
    int st = nodeptr[n], en = nodeptr[n + 1];
    float acc = (q == 0) ? tv[n] : 0.0f;
    int e = st + q;
    for (; e + 4 < en; e += 8) {
        int2 q0 = srec[e], q1 = srec[e + 4];
        float t0 = tv[q0.x], t1 = tv[q1.x];
        acc = fmaf(__int_as_float(q0.y), t0, acc);
        acc = fmaf(__int_as_float(q1.y), t1, acc);
    }
    if (e < en) {
        int2 qq = srec[e];
        acc = fmaf(__int_as_float(qq.y), tv[qq.x], acc);
    }
    acc += __shfl_xor(acc, 1);
    acc += __shfl_xor(acc, 2);
    if (q == 0) out[n] = b2[0] + dinv[n] * acc;
}

extern "C" void kernel_launch(void* const* d_in, const int* in_sizes, int n_in,
                              void* d_out, int out_size, void* d_ws, size_t ws_size,
                              hipStream_t stream) {
    const float* x  = (const float*)d_in[0];
    const int*   ei = (const int*)d_in[1];    // [2, E] int32
    const float* w  = (const float*)d_in[2];
    const float* W1 = (const float*)d_in[3];
    const float* b1 = (const float*)d_in[4];
    const float* W2 = (const float*)d_in[5];
    const float* b2 = (const float*)d_in[6];
    float* out = (float*)d_out;

    const int* row = ei;
    const int* col = ei + E_;

    // ws (ints): countsA[CA*BK]=1024000 | countsP[1024000] | grptot[20480] |
    //   baseB[2049 pad 2560] | nodeptr[100352] | dinv[N] | xw[8N] | tv[N] |
    //   brec[E] int2                                       ~38 MB
    int*   wsI     = (int*)d_ws;
    int*   countsA = wsI;
    int*   countsP = wsI + (size_t)CA * BK;          // 1024000
    int*   grptot  = countsP + (size_t)CA * BK;      // +1024000
    int*   baseB   = grptot + GG * BK;               // +20480
    int*   nodeptr = baseB + 2560;
    float* dinv    = (float*)(nodeptr + 100352);
    float* xw      = dinv + N_;
    float* tv      = xw + (size_t)8 * N_;
    int2*  brec    = (int2*)(tv + N_);

    kA_hist    <<<CA, 512, 0, stream>>>(col, countsA);
    kA_scan1   <<<(GG * BK + 255) / 256, 256, 0, stream>>>(countsA, countsP, grptot);
    kA_scan2B  <<<1, 1024, 0, stream>>>(grptot, baseB);
    kA_scatter2<<<CA, 512, 0, stream>>>(row, col, w, countsA, countsP, grptot, brec);
    kB_sortdeg <<<NBUCK, 256, 0, stream>>>(baseB, brec, x, dinv, xw, nodeptr);
    kB2_node   <<<NBLK4, 512, 0, stream>>>(nodeptr, brec, dinv, xw, W1, b1, W2, tv);
    kB3_node   <<<NBLK4, 512, 0, stream>>>(nodeptr, brec, dinv, tv, b2, out);
}

// Round 15
// 211.111 us; speedup vs baseline: 1.1796x; 1.0127x over previous
//
#include <hip/hip_runtime.h>

// GCN 2-layer: N=100000, E=3200000, IN=8, HID=64, OUT=1.
// Round 15: sortdeg ping-pong + 8-threads/node B kernels.
//  R14: 214us, all top dispatches are harness ws-poison fills; largest own
//  kernel is kB_sortdeg (~25.8KB LDS staging, 256 thr, 3 LDS-atomic/rec).
//  Now: sortdeg writes sorted records to a second global buffer srt
//  (removes the LDS raw[] staging that only existed to avoid in-place
//  races, and the CAP guard), 512 thr, LDS ~2.3KB -> wave-capped occupancy.
//  kB2/kB3: 8 thr/node (64 nodes/block, 1563 blocks = full subscription).

#define N_    100000
#define E_    3200000
#define BK    2048        // buckets = col >> 6 (64 nodes/bucket)
#define NBUCK 1563        // ceil(N_/64)
#define CA    500         // chunks (= scatter blocks)
#define CSA   6400        // E_/CA
#define GG    10          // chunk groups
#define GCH   50          // chunks per group
#define SCE   6400        // edges per scatter block

// ---- A1: per-(chunk,bucket) histogram. countsA chunk-major [c][b], RAW.
__global__ void kA_hist(const int* __restrict__ col, int* __restrict__ countsA) {
    __shared__ int bins[BK];
    int c = blockIdx.x, t = threadIdx.x;
    for (int i = t; i < BK; i += 512) bins[i] = 0;
    __syncthreads();
    const int* cp = col + c * CSA;
    #pragma unroll
    for (int it = 0; it < 3; it++) {            // 3 x 4 x 512 = 6144
        int e = t + it * 2048;
        int v0 = cp[e], v1 = cp[e + 512], v2 = cp[e + 1024], v3 = cp[e + 1536];
        atomicAdd(&bins[v0 >> 6], 1);
        atomicAdd(&bins[v1 >> 6], 1);
        atomicAdd(&bins[v2 >> 6], 1);
        atomicAdd(&bins[v3 >> 6], 1);
    }
    if (t < 256) atomicAdd(&bins[cp[6144 + t] >> 6], 1);
    __syncthreads();
    int* outp = countsA + (size_t)c * BK;
    for (int i = t; i < BK; i += 512) outp[i] = bins[i];
}

// ---- A2a: within-group exclusive prefix across chunks (raw in, prefix out).
__global__ void kA_scan1(const int* __restrict__ countsA, int* __restrict__ countsP,
                         int* __restrict__ grptot) {
    int tid = blockIdx.x * 256 + threadIdx.x;   // GG*BK = 20480 threads
    if (tid >= GG * BK) return;
    int g = tid >> 11;
    int b = tid & (BK - 1);
    int c0 = g * GCH;
    int run = 0;
    #pragma unroll 5
    for (int k = 0; k < GCH; k++) {
        size_t idx = (size_t)(c0 + k) * BK + b;
        int v = countsA[idx];
        countsP[idx] = run;
        run += v;
    }
    grptot[g * BK + b] = run;
}

// ---- A2b (one block): scan grptot across groups, bucket-base scan, fold.
__global__ void kA_scan2B(int* __restrict__ grptot, int* __restrict__ baseB) {
    __shared__ int sm[1024];
    int t = threadIdx.x;
    int tot0, tot1;
    {
        int b = 2 * t, run = 0;
        #pragma unroll
        for (int g = 0; g < GG; g++) {
            int idx = g * BK + b;
            int v = grptot[idx];
            grptot[idx] = run;
            run += v;
        }
        tot0 = run;
    }
    {
        int b = 2 * t + 1, run = 0;
        #pragma unroll
        for (int g = 0; g < GG; g++) {
            int idx = g * BK + b;
            int v = grptot[idx];
            grptot[idx] = run;
            run += v;
        }
        tot1 = run;
    }
    int pair = tot0 + tot1;
    sm[t] = pair;
    __syncthreads();
    for (int off = 1; off < 1024; off <<= 1) {
        int add = (t >= off) ? sm[t - off] : 0;
        __syncthreads();
        sm[t] += add;
        __syncthreads();
    }
    int excl = sm[t] - pair;
    baseB[2 * t]     = excl;
    baseB[2 * t + 1] = excl + tot0;
    if (t == 1023) baseB[BK] = sm[1023];
    #pragma unroll
    for (int g = 0; g < GG; g++) {
        grptot[g * BK + 2 * t]     += excl;
        grptot[g * BK + 2 * t + 1] += excl + tot0;
    }
}

// ---- A3: LDS bucket-sort 6400 edges, run-contiguous global writes.
__global__ __launch_bounds__(512)
void kA_scatter2(const int* __restrict__ row, const int* __restrict__ col,
                 const float* __restrict__ w,
                 const int* __restrict__ countsA, const int* __restrict__ countsP,
                 const int* __restrict__ grptot,
                 int2* __restrict__ brec) {
    __shared__ int  lh[BK];                 // shift
    __shared__ int  lc_[BK];                // local base -> bump cursor
    __shared__ int2 srec[SCE];              // 51200 B
    __shared__ unsigned short sbid[SCE];    // 12800 B (scan scratch aliased)
    int* part = (int*)sbid;                 // 512 ints, used before pass 2
    int c = blockIdx.x, t = threadIdx.x;
    int g = c / GCH;
    int E0 = c * SCE;
    const int4* rawp = (const int4*)(countsA + (size_t)c * BK);
    int4 hv = rawp[t];
    int tot = hv.x + hv.y + hv.z + hv.w;
    part[t] = tot;
    __syncthreads();
    for (int off = 1; off < 512; off <<= 1) {
        int add = (t >= off) ? part[t - off] : 0;
        __syncthreads();
        part[t] += add;
        __syncthreads();
    }
    int excl = part[t] - tot;
    int b0 = t * 4;
    lc_[b0]     = excl;
    lc_[b0 + 1] = excl + hv.x;
    lc_[b0 + 2] = excl + hv.x + hv.y;
    lc_[b0 + 3] = excl + hv.x + hv.y + hv.z;
    __syncthreads();
    const int* gO = grptot + g * BK;
    const int* gP = countsP + (size_t)c * BK;
    for (int i = t; i < BK; i += 512) lh[i] = gO[i] + gP[i] - lc_[i];
    __syncthreads();
    const int* cp = col + E0;
    const int* rp = row + E0;
    const float* wp = w + E0;
    #pragma unroll 4
    for (int i = t; i < SCE; i += 512) {
        int v = cp[i];
        int b = v >> 6;
        int lp = atomicAdd(&lc_[b], 1);
        srec[lp] = make_int2(rp[i] | ((v & 63) << 17), __float_as_int(wp[i]));
        sbid[lp] = (unsigned short)b;
    }
    __syncthreads();
    #pragma unroll 4
    for (int j = t; j < SCE; j += 512) {
        brec[lh[sbid[j]] + j] = srec[j];
    }
}

// ---- B-sort: per-bucket counting sort brec -> srt (+ CSR, deg, dinv, xw).
//   No LDS staging (global ping-pong), no capacity guard; 512 threads.
__global__ __launch_bounds__(512)
void kB_sortdeg(const int* __restrict__ baseB, const int2* __restrict__ brec,
                int2* __restrict__ srt,
                const float* __restrict__ x,
                float* __restrict__ dinv, float* __restrict__ xw,
                int* __restrict__ nodeptr) {
    __shared__ int   h[8 * 64];        // wave-private bins
    __shared__ float degw[8 * 64];
    __shared__ int   nb[65];
    int b = blockIdx.x, t = threadIdx.x;
    int wid = t >> 6;                  // 0..7
    int st = baseB[b];
    int cnt = baseB[b + 1] - st;
    h[t] = 0;
    degw[t] = 0.0f;
    __syncthreads();
    int hb = wid << 6;
    int i = t;
    for (; i + 512 < cnt; i += 1024) {
        int2 q0 = brec[st + i], q1 = brec[st + i + 512];
        atomicAdd(&h[hb + (q0.x >> 17)], 1);
        atomicAdd(&h[hb + (q1.x >> 17)], 1);
        atomicAdd(&degw[hb + (q0.x >> 17)], __int_as_float(q0.y));
        atomicAdd(&degw[hb + (q1.x >> 17)], __int_as_float(q1.y));
    }
    for (; i < cnt; i += 512) {
        int2 q = brec[st + i];
        atomicAdd(&h[hb + (q.x >> 17)], 1);
        atomicAdd(&degw[hb + (q.x >> 17)], __int_as_float(q.y));
    }
    __syncthreads();
    if (t < 64) {
        int off = 0;
        #pragma unroll
        for (int w2 = 0; w2 < 8; w2++) {
            int cc = h[(w2 << 6) + t];
            h[(w2 << 6) + t] = off;
            off += cc;
        }
        int val = off;
        #pragma unroll
        for (int d = 1; d < 64; d <<= 1) {
            int u = __shfl_up(val, d);
            if (t >= d) val += u;
        }
        nb[t] = val - off;
        if (t == 63) nb[64] = val;
    }
    __syncthreads();
    if (t < 64) {
        int e2 = nb[t];
        #pragma unroll
        for (int w2 = 0; w2 < 8; w2++) h[(w2 << 6) + t] += e2;
    }
    __syncthreads();
    i = t;
    for (; i + 512 < cnt; i += 1024) {
        int2 q0 = brec[st + i], q1 = brec[st + i + 512];
        int p0 = atomicAdd(&h[hb + (q0.x >> 17)], 1);
        srt[st + p0] = make_int2(q0.x & 0x1FFFF, q0.y);
        int p1 = atomicAdd(&h[hb + (q1.x >> 17)], 1);
        srt[st + p1] = make_int2(q1.x & 0x1FFFF, q1.y);
    }
    for (; i < cnt; i += 512) {
        int2 q = brec[st + i];
        int pos = atomicAdd(&h[hb + (q.x >> 17)], 1);
        srt[st + pos] = make_int2(q.x & 0x1FFFF, q.y);
    }
    if (t < 64) {
        int n = (b << 6) + t;
        if (n < N_) {
            float d = degw[t]       + degw[64 + t]  + degw[128 + t] + degw[192 + t]
                    + degw[256 + t] + degw[320 + t] + degw[384 + t] + degw[448 + t];
            float di = rsqrtf(d + 1.0f);
            dinv[n] = di;
            nodeptr[n] = st + nb[t];
            const float4* xi = (const float4*)(x + (size_t)n * 8);
            float4 xa = xi[0], xb = xi[1];
            float4* o = (float4*)(xw + (size_t)n * 8);
            o[0] = make_float4(di * xa.x, di * xa.y, di * xa.z, di * xa.w);
            o[1] = make_float4(di * xb.x, di * xb.y, di * xb.z, di * xb.w);
        }
        if (b == NBUCK - 1 && t == 0) nodeptr[N_] = E_;
    }
}

// ---- B2: 8 threads/node register aggregation + split MLP. Zero atomics.
__global__ __launch_bounds__(512)
void kB2_node(const int* __restrict__ nodeptr, const int2* __restrict__ srec,
              const float* __restrict__ dinv,
              const float* __restrict__ xw,
              const float* __restrict__ W1,
              const float* __restrict__ b1,
              const float* __restrict__ W2,
              float* __restrict__ tv) {
    __shared__ float sW1[8 * 64];
    __shared__ float sb1[64];
    __shared__ float sW2[64];
    int t = threadIdx.x;                  // 512 threads, 64 nodes/block
    sW1[t] = W1[t];
    if (t < 64) { sb1[t] = b1[t]; sW2[t] = W2[t]; }
    __syncthreads();
    int n = blockIdx.x * 64 + (t >> 3);
    int q = t & 7;
    if (n >= N_) return;
    int st = nodeptr[n], en = nodeptr[n + 1];
    const float4* xw4 = (const float4*)xw;
    float a[8];
    if (q == 0) {
        float4 s0 = xw4[2 * n], s1 = xw4[2 * n + 1];
        a[0] = s0.x; a[1] = s0.y; a[2] = s0.z; a[3] = s0.w;
        a[4] = s1.x; a[5] = s1.y; a[6] = s1.z; a[7] = s1.w;
    } else {
        #pragma unroll
        for (int k = 0; k < 8; k++) a[k] = 0.0f;
    }
    int e = st + q;
    for (; e + 8 < en; e += 16) {         // 2 edges per iter (stride 8)
        int2 q0 = srec[e], q1 = srec[e + 8];
        float4 f0a = xw4[2 * q0.x], f0b = xw4[2 * q0.x + 1];
        float4 f1a = xw4[2 * q1.x], f1b = xw4[2 * q1.x + 1];
        float w0 = __int_as_float(q0.y), w1 = __int_as_float(q1.y);
        a[0] = fmaf(w0, f0a.x, a[0]); a[1] = fmaf(w0, f0a.y, a[1]);
        a[2] = fmaf(w0, f0a.z, a[2]); a[3] = fmaf(w0, f0a.w, a[3]);
        a[4] = fmaf(w0, f0b.x, a[4]); a[5] = fmaf(w0, f0b.y, a[5]);
        a[6] = fmaf(w0, f0b.z, a[6]); a[7] = fmaf(w0, f0b.w, a[7]);
        a[0] = fmaf(w1, f1a.x, a[0]); a[1] = fmaf(w1, f1a.y, a[1]);
        a[2] = fmaf(w1, f1a.z, a[2]); a[3] = fmaf(w1, f1a.w, a[3]);
        a[4] = fmaf(w1, f1b.x, a[4]); a[5] = fmaf(w1, f1b.y, a[5]);
        a[6] = fmaf(w1, f1b.z, a[6]); a[7] = fmaf(w1, f1b.w, a[7]);
    }
    if (e < en) {
        int2 qq = srec[e];
        float4 fa = xw4[2 * qq.x], fb = xw4[2 * qq.x + 1];
        float w0 = __int_as_float(qq.y);
        a[0] = fmaf(w0, fa.x, a[0]); a[1] = fmaf(w0, fa.y, a[1]);
        a[2] = fmaf(w0, fa.z, a[2]); a[3] = fmaf(w0, fa.w, a[3]);
        a[4] = fmaf(w0, fb.x, a[4]); a[5] = fmaf(w0, fb.y, a[5]);
        a[6] = fmaf(w0, fb.z, a[6]); a[7] = fmaf(w0, fb.w, a[7]);
    }
    // reduce a[] across the 8 lanes of this node
    #pragma unroll
    for (int k = 0; k < 8; k++) {
        a[k] += __shfl_xor(a[k], 1);
        a[k] += __shfl_xor(a[k], 2);
        a[k] += __shfl_xor(a[k], 4);
    }
    float di = dinv[n];
    #pragma unroll
    for (int k = 0; k < 8; k++) a[k] *= di;
    // split MLP: lane q -> j = 8q .. 8q+7
    float sv = 0.0f;
    int jb = q << 3;
    #pragma unroll
    for (int j = 0; j < 8; j++) {
        int jj = jb + j;
        float h = sb1[jj];
        #pragma unroll
        for (int k = 0; k < 8; k++) h = fmaf(a[k], sW1[k * 64 + jj], h);
        sv = fmaf(fmaxf(h, 0.0f), sW2[jj], sv);
    }
    sv += __shfl_xor(sv, 1);
    sv += __shfl_xor(sv, 2);
    sv += __shfl_xor(sv, 4);
    if (q == 0) tv[n] = di * sv;
}

// ---- B3: 8 threads/node layer-2.
__global__ __launch_bounds__(512)
void kB3_node(const int* __restrict__ nodeptr, const int2* __restrict__ srec,
              const float* __restrict__ dinv,
              const float* __restrict__ tv,
              const float* __restrict__ b2,
              float* __restrict__ out) {
    int t = threadIdx.x;                  // 512 threads, 64 nodes/block
    int n = blockIdx.x * 64 + (t >> 3);
    int q = t & 7;
    if (n >= N_) return;
    int st = nodeptr[n], en = nodeptr[n + 1];
    float acc = (q == 0) ? tv[n] : 0.0f;
    int e = st + q;
    for (; e + 8 < en; e += 16) {         // 2 edges per iter (stride 8)
        int2 q0 = srec[e], q1 = srec[e + 8];
        float t0 = tv[q0.x], t1 = tv[q1.x];
        acc = fmaf(__int_as_float(q0.y), t0, acc);
        acc = fmaf(__int_as_float(q1.y), t1, acc);
    }
    if (e < en) {
        int2 qq = srec[e];
        acc = fmaf(__int_as_float(qq.y), tv[qq.x], acc);
    }
    acc += __shfl_xor(acc, 1);
    acc += __shfl_xor(acc, 2);
    acc += __shfl_xor(acc, 4);
    if (q == 0) out[n] = b2[0] + dinv[n] * acc;
}

extern "C" void kernel_launch(void* const* d_in, const int* in_sizes, int n_in,
                              void* d_out, int out_size, void* d_ws, size_t ws_size,
                              hipStream_t stream) {
    const float* x  = (const float*)d_in[0];
    const int*   ei = (const int*)d_in[1];    // [2, E] int32
    const float* w  = (const float*)d_in[2];
    const float* W1 = (const float*)d_in[3];
    const float* b1 = (const float*)d_in[4];
    const float* W2 = (const float*)d_in[5];
    const float* b2 = (const float*)d_in[6];
    float* out = (float*)d_out;

    const int* row = ei;
    const int* col = ei + E_;

    // ws (ints): countsA[1024000] | countsP[1024000] | grptot[20480] |
    //   baseB[2049 pad 2560] | nodeptr[100352] | dinv[N] | xw[8N] | tv[N] |
    //   brec[E] int2 | srt[E] int2                         ~64 MB
    int*   wsI     = (int*)d_ws;
    int*   countsA = wsI;
    int*   countsP = wsI + (size_t)CA * BK;          // 1024000
    int*   grptot  = countsP + (size_t)CA * BK;      // +1024000
    int*   baseB   = grptot + GG * BK;               // +20480
    int*   nodeptr = baseB + 2560;
    float* dinv    = (float*)(nodeptr + 100352);
    float* xw      = dinv + N_;
    float* tv      = xw + (size_t)8 * N_;
    int2*  brec    = (int2*)(tv + N_);
    int2*  srt     = brec + E_;

    kA_hist    <<<CA, 512, 0, stream>>>(col, countsA);
    kA_scan1   <<<(GG * BK + 255) / 256, 256, 0, stream>>>(countsA, countsP, grptot);
    kA_scan2B  <<<1, 1024, 0, stream>>>(grptot, baseB);
    kA_scatter2<<<CA, 512, 0, stream>>>(row, col, w, countsA, countsP, grptot, brec);
    kB_sortdeg <<<NBUCK, 512, 0, stream>>>(baseB, brec, srt, x, dinv, xw, nodeptr);
    kB2_node   <<<NBUCK, 512, 0, stream>>>(nodeptr, srt, dinv, xw, W1, b1, W2, tv);
    kB3_node   <<<NBUCK, 512, 0, stream>>>(nodeptr, srt, dinv, tv, b2, out);
}

// Round 16
// 201.385 us; speedup vs baseline: 1.2366x; 1.0483x over previous
//
#include <hip/hip_runtime.h>

// GCN 2-layer: N=100000, E=3200000, IN=8, HID=64, OUT=1.
// Round 16: R15 pipeline with (1) single-pass sortdeg — per-thread records
// held in registers between hist and scatter passes (bucket cnt <= ~2300 <
// 512*5, global fallback never taken statistically), removing the 2nd
// 25.6MB brec read; (2) wave-shfl scans in scatter2/scan2B (2 barriers
// instead of 9-10). kB2/kB3 8-thr/node, run-coalesced scatter unchanged.

#define N_    100000
#define E_    3200000
#define BK    2048        // buckets = col >> 6 (64 nodes/bucket)
#define NBUCK 1563        // ceil(N_/64)
#define CA    500         // chunks (= scatter blocks)
#define CSA   6400        // E_/CA
#define GG    10          // chunk groups
#define GCH   50          // chunks per group
#define SCE   6400        // edges per scatter block

// ---- A1: per-(chunk,bucket) histogram. countsA chunk-major [c][b], RAW.
__global__ void kA_hist(const int* __restrict__ col, int* __restrict__ countsA) {
    __shared__ int bins[BK];
    int c = blockIdx.x, t = threadIdx.x;
    for (int i = t; i < BK; i += 512) bins[i] = 0;
    __syncthreads();
    const int* cp = col + c * CSA;
    #pragma unroll
    for (int it = 0; it < 3; it++) {            // 3 x 4 x 512 = 6144
        int e = t + it * 2048;
        int v0 = cp[e], v1 = cp[e + 512], v2 = cp[e + 1024], v3 = cp[e + 1536];
        atomicAdd(&bins[v0 >> 6], 1);
        atomicAdd(&bins[v1 >> 6], 1);
        atomicAdd(&bins[v2 >> 6], 1);
        atomicAdd(&bins[v3 >> 6], 1);
    }
    if (t < 256) atomicAdd(&bins[cp[6144 + t] >> 6], 1);
    __syncthreads();
    int* outp = countsA + (size_t)c * BK;
    for (int i = t; i < BK; i += 512) outp[i] = bins[i];
}

// ---- A2a: within-group exclusive prefix across chunks (raw in, prefix out).
__global__ void kA_scan1(const int* __restrict__ countsA, int* __restrict__ countsP,
                         int* __restrict__ grptot) {
    int tid = blockIdx.x * 256 + threadIdx.x;   // GG*BK = 20480 threads
    if (tid >= GG * BK) return;
    int g = tid >> 11;
    int b = tid & (BK - 1);
    int c0 = g * GCH;
    int run = 0;
    #pragma unroll 5
    for (int k = 0; k < GCH; k++) {
        size_t idx = (size_t)(c0 + k) * BK + b;
        int v = countsA[idx];
        countsP[idx] = run;
        run += v;
    }
    grptot[g * BK + b] = run;
}

// ---- A2b (one block): scan grptot across groups, bucket-base scan, fold.
__global__ void kA_scan2B(int* __restrict__ grptot, int* __restrict__ baseB) {
    __shared__ int wsum[16];
    int t = threadIdx.x;
    int tot0, tot1;
    {
        int b = 2 * t, run = 0;
        #pragma unroll
        for (int g = 0; g < GG; g++) {
            int idx = g * BK + b;
            int v = grptot[idx];
            grptot[idx] = run;
            run += v;
        }
        tot0 = run;
    }
    {
        int b = 2 * t + 1, run = 0;
        #pragma unroll
        for (int g = 0; g < GG; g++) {
            int idx = g * BK + b;
            int v = grptot[idx];
            grptot[idx] = run;
            run += v;
        }
        tot1 = run;
    }
    int pair = tot0 + tot1;
    int lane = t & 63, wv = t >> 6;
    int val = pair;
    #pragma unroll
    for (int d = 1; d < 64; d <<= 1) {
        int u = __shfl_up(val, d);
        if (lane >= d) val += u;
    }
    if (lane == 63) wsum[wv] = val;
    __syncthreads();
    if (t == 0) {
        int run = 0;
        #pragma unroll
        for (int g2 = 0; g2 < 16; g2++) { int v = wsum[g2]; wsum[g2] = run; run += v; }
    }
    __syncthreads();
    int excl = val - pair + wsum[wv];
    baseB[2 * t]     = excl;
    baseB[2 * t + 1] = excl + tot0;
    if (t == 1023) baseB[BK] = wsum[15] + __shfl(val, 63);   // total = E_
    #pragma unroll
    for (int g = 0; g < GG; g++) {
        grptot[g * BK + 2 * t]     += excl;
        grptot[g * BK + 2 * t + 1] += excl + tot0;
    }
}

// ---- A3: LDS bucket-sort 6400 edges, run-contiguous global writes.
__global__ __launch_bounds__(512)
void kA_scatter2(const int* __restrict__ row, const int* __restrict__ col,
                 const float* __restrict__ w,
                 const int* __restrict__ countsA, const int* __restrict__ countsP,
                 const int* __restrict__ grptot,
                 int2* __restrict__ brec) {
    __shared__ int  lh[BK];                 // shift
    __shared__ int  lc_[BK];                // local base -> bump cursor
    __shared__ int  wsum[8];
    __shared__ int2 srec[SCE];              // 51200 B
    __shared__ unsigned short sbid[SCE];    // 12800 B
    int c = blockIdx.x, t = threadIdx.x;
    int g = c / GCH;
    int E0 = c * SCE;
    const int4* rawp = (const int4*)(countsA + (size_t)c * BK);
    int4 hv = rawp[t];
    int tot = hv.x + hv.y + hv.z + hv.w;
    // wave-shfl scan of tot over 512 threads
    int lane = t & 63, wv = t >> 6;
    int val = tot;
    #pragma unroll
    for (int d = 1; d < 64; d <<= 1) {
        int u = __shfl_up(val, d);
        if (lane >= d) val += u;
    }
    if (lane == 63) wsum[wv] = val;
    __syncthreads();
    if (t == 0) {
        int run = 0;
        #pragma unroll
        for (int g2 = 0; g2 < 8; g2++) { int v = wsum[g2]; wsum[g2] = run; run += v; }
    }
    __syncthreads();
    int excl = val - tot + wsum[wv];
    int b0 = t * 4;
    lc_[b0]     = excl;
    lc_[b0 + 1] = excl + hv.x;
    lc_[b0 + 2] = excl + hv.x + hv.y;
    lc_[b0 + 3] = excl + hv.x + hv.y + hv.z;
    __syncthreads();
    const int* gO = grptot + g * BK;
    const int* gP = countsP + (size_t)c * BK;
    for (int i = t; i < BK; i += 512) lh[i] = gO[i] + gP[i] - lc_[i];
    __syncthreads();
    const int* cp = col + E0;
    const int* rp = row + E0;
    const float* wp = w + E0;
    #pragma unroll 4
    for (int i = t; i < SCE; i += 512) {
        int v = cp[i];
        int b = v >> 6;
        int lp = atomicAdd(&lc_[b], 1);
        srec[lp] = make_int2(rp[i] | ((v & 63) << 17), __float_as_int(wp[i]));
        sbid[lp] = (unsigned short)b;
    }
    __syncthreads();
    #pragma unroll 4
    for (int j = t; j < SCE; j += 512) {
        brec[lh[sbid[j]] + j] = srec[j];
    }
}

// ---- B-sort: per-bucket counting sort brec -> srt, single global pass
//   (records parked in registers between hist and scatter). + CSR/deg/dinv/xw.
__global__ __launch_bounds__(512)
void kB_sortdeg(const int* __restrict__ baseB, const int2* __restrict__ brec,
                int2* __restrict__ srt,
                const float* __restrict__ x,
                float* __restrict__ dinv, float* __restrict__ xw,
                int* __restrict__ nodeptr) {
    __shared__ int   h[8 * 64];        // wave-private bins
    __shared__ float degw[8 * 64];
    __shared__ int   nb[65];
    int b = blockIdx.x, t = threadIdx.x;
    int wid = t >> 6;                  // 0..7
    int st = baseB[b];
    int cnt = baseB[b + 1] - st;
    h[t] = 0;
    degw[t] = 0.0f;
    __syncthreads();
    int hb = wid << 6;
    // predicated independent loads: up to 5 records/thread in registers
    bool p0 = t < cnt, p1 = t + 512 < cnt, p2 = t + 1024 < cnt,
         p3 = t + 1536 < cnt, p4 = t + 2048 < cnt;
    int2 q0 = p0 ? brec[st + t]        : make_int2(0, 0);
    int2 q1 = p1 ? brec[st + t + 512]  : make_int2(0, 0);
    int2 q2 = p2 ? brec[st + t + 1024] : make_int2(0, 0);
    int2 q3 = p3 ? brec[st + t + 1536] : make_int2(0, 0);
    int2 q4 = p4 ? brec[st + t + 2048] : make_int2(0, 0);
    if (p0) { atomicAdd(&h[hb + (q0.x >> 17)], 1); atomicAdd(&degw[hb + (q0.x >> 17)], __int_as_float(q0.y)); }
    if (p1) { atomicAdd(&h[hb + (q1.x >> 17)], 1); atomicAdd(&degw[hb + (q1.x >> 17)], __int_as_float(q1.y)); }
    if (p2) { atomicAdd(&h[hb + (q2.x >> 17)], 1); atomicAdd(&degw[hb + (q2.x >> 17)], __int_as_float(q2.y)); }
    if (p3) { atomicAdd(&h[hb + (q3.x >> 17)], 1); atomicAdd(&degw[hb + (q3.x >> 17)], __int_as_float(q3.y)); }
    if (p4) { atomicAdd(&h[hb + (q4.x >> 17)], 1); atomicAdd(&degw[hb + (q4.x >> 17)], __int_as_float(q4.y)); }
    // fallback for cnt > 2560 (statistically never: mean 2048, sd ~45)
    for (int i = t + 2560; i < cnt; i += 512) {
        int2 q = brec[st + i];
        atomicAdd(&h[hb + (q.x >> 17)], 1);
        atomicAdd(&degw[hb + (q.x >> 17)], __int_as_float(q.y));
    }
    __syncthreads();
    if (t < 64) {
        int off = 0;
        #pragma unroll
        for (int w2 = 0; w2 < 8; w2++) {
            int cc = h[(w2 << 6) + t];
            h[(w2 << 6) + t] = off;
            off += cc;
        }
        int val = off;
        #pragma unroll
        for (int d = 1; d < 64; d <<= 1) {
            int u = __shfl_up(val, d);
            if (t >= d) val += u;
        }
        nb[t] = val - off;
        if (t == 63) nb[64] = val;
    }
    __syncthreads();
    if (t < 64) {
        int e2 = nb[t];
        #pragma unroll
        for (int w2 = 0; w2 < 8; w2++) h[(w2 << 6) + t] += e2;
    }
    __syncthreads();
    // scatter from registers (no second global read)
    if (p0) { int p = atomicAdd(&h[hb + (q0.x >> 17)], 1); srt[st + p] = make_int2(q0.x & 0x1FFFF, q0.y); }
    if (p1) { int p = atomicAdd(&h[hb + (q1.x >> 17)], 1); srt[st + p] = make_int2(q1.x & 0x1FFFF, q1.y); }
    if (p2) { int p = atomicAdd(&h[hb + (q2.x >> 17)], 1); srt[st + p] = make_int2(q2.x & 0x1FFFF, q2.y); }
    if (p3) { int p = atomicAdd(&h[hb + (q3.x >> 17)], 1); srt[st + p] = make_int2(q3.x & 0x1FFFF, q3.y); }
    if (p4) { int p = atomicAdd(&h[hb + (q4.x >> 17)], 1); srt[st + p] = make_int2(q4.x & 0x1FFFF, q4.y); }
    for (int i = t + 2560; i < cnt; i += 512) {
        int2 q = brec[st + i];
        int pos = atomicAdd(&h[hb + (q.x >> 17)], 1);
        srt[st + pos] = make_int2(q.x & 0x1FFFF, q.y);
    }
    if (t < 64) {
        int n = (b << 6) + t;
        if (n < N_) {
            float d = degw[t]       + degw[64 + t]  + degw[128 + t] + degw[192 + t]
                    + degw[256 + t] + degw[320 + t] + degw[384 + t] + degw[448 + t];
            float di = rsqrtf(d + 1.0f);
            dinv[n] = di;
            nodeptr[n] = st + nb[t];
            const float4* xi = (const float4*)(x + (size_t)n * 8);
            float4 xa = xi[0], xb = xi[1];
            float4* o = (float4*)(xw + (size_t)n * 8);
            o[0] = make_float4(di * xa.x, di * xa.y, di * xa.z, di * xa.w);
            o[1] = make_float4(di * xb.x, di * xb.y, di * xb.z, di * xb.w);
        }
        if (b == NBUCK - 1 && t == 0) nodeptr[N_] = E_;
    }
}

// ---- B2: 8 threads/node register aggregation + split MLP. Zero atomics.
__global__ __launch_bounds__(512)
void kB2_node(const int* __restrict__ nodeptr, const int2* __restrict__ srec,
              const float* __restrict__ dinv,
              const float* __restrict__ xw,
              const float* __restrict__ W1,
              const float* __restrict__ b1,
              const float* __restrict__ W2,
              float* __restrict__ tv) {
    __shared__ float sW1[8 * 64];
    __shared__ float sb1[64];
    __shared__ float sW2[64];
    int t = threadIdx.x;                  // 512 threads, 64 nodes/block
    sW1[t] = W1[t];
    if (t < 64) { sb1[t] = b1[t]; sW2[t] = W2[t]; }
    __syncthreads();
    int n = blockIdx.x * 64 + (t >> 3);
    int q = t & 7;
    if (n >= N_) return;
    int st = nodeptr[n], en = nodeptr[n + 1];
    const float4* xw4 = (const float4*)xw;
    float a[8];
    if (q == 0) {
        float4 s0 = xw4[2 * n], s1 = xw4[2 * n + 1];
        a[0] = s0.x; a[1] = s0.y; a[2] = s0.z; a[3] = s0.w;
        a[4] = s1.x; a[5] = s1.y; a[6] = s1.z; a[7] = s1.w;
    } else {
        #pragma unroll
        for (int k = 0; k < 8; k++) a[k] = 0.0f;
    }
    int e = st + q;
    for (; e + 8 < en; e += 16) {         // 2 edges per iter (stride 8)
        int2 q0 = srec[e], q1 = srec[e + 8];
        float4 f0a = xw4[2 * q0.x], f0b = xw4[2 * q0.x + 1];
        float4 f1a = xw4[2 * q1.x], f1b = xw4[2 * q1.x + 1];
        float w0 = __int_as_float(q0.y), w1 = __int_as_float(q1.y);
        a[0] = fmaf(w0, f0a.x, a[0]); a[1] = fmaf(w0, f0a.y, a[1]);
        a[2] = fmaf(w0, f0a.z, a[2]); a[3] = fmaf(w0, f0a.w, a[3]);
        a[4] = fmaf(w0, f0b.x, a[4]); a[5] = fmaf(w0, f0b.y, a[5]);
        a[6] = fmaf(w0, f0b.z, a[6]); a[7] = fmaf(w0, f0b.w, a[7]);
        a[0] = fmaf(w1, f1a.x, a[0]); a[1] = fmaf(w1, f1a.y, a[1]);
        a[2] = fmaf(w1, f1a.z, a[2]); a[3] = fmaf(w1, f1a.w, a[3]);
        a[4] = fmaf(w1, f1b.x, a[4]); a[5] = fmaf(w1, f1b.y, a[5]);
        a[6] = fmaf(w1, f1b.z, a[6]); a[7] = fmaf(w1, f1b.w, a[7]);
    }
    if (e < en) {
        int2 qq = srec[e];
        float4 fa = xw4[2 * qq.x], fb = xw4[2 * qq.x + 1];
        float w0 = __int_as_float(qq.y);
        a[0] = fmaf(w0, fa.x, a[0]); a[1] = fmaf(w0, fa.y, a[1]);
        a[2] = fmaf(w0, fa.z, a[2]); a[3] = fmaf(w0, fa.w, a[3]);
        a[4] = fmaf(w0, fb.x, a[4]); a[5] = fmaf(w0, fb.y, a[5]);
        a[6] = fmaf(w0, fb.z, a[6]); a[7] = fmaf(w0, fb.w, a[7]);
    }
    #pragma unroll
    for (int k = 0; k < 8; k++) {
        a[k] += __shfl_xor(a[k], 1);
        a[k] += __shfl_xor(a[k], 2);
        a[k] += __shfl_xor(a[k], 4);
    }
    float di = dinv[n];
    #pragma unroll
    for (int k = 0; k < 8; k++) a[k] *= di;
    float sv = 0.0f;
    int jb = q << 3;
    #pragma unroll
    for (int j = 0; j < 8; j++) {
        int jj = jb + j;
        float h = sb1[jj];
        #pragma unroll
        for (int k = 0; k < 8; k++) h = fmaf(a[k], sW1[k * 64 + jj], h);
        sv = fmaf(fmaxf(h, 0.0f), sW2[jj], sv);
    }
    sv += __shfl_xor(sv, 1);
    sv += __shfl_xor(sv, 2);
    sv += __shfl_xor(sv, 4);
    if (q == 0) tv[n] = di * sv;
}

// ---- B3: 8 threads/node layer-2.
__global__ __launch_bounds__(512)
void kB3_node(const int* __restrict__ nodeptr, const int2* __restrict__ srec,
              const float* __restrict__ dinv,
              const float* __restrict__ tv,
              const float* __restrict__ b2,
              float* __restrict__ out) {
    int t = threadIdx.x;                  // 512 threads, 64 nodes/block
    int n = blockIdx.x * 64 + (t >> 3);
    int q = t & 7;
    if (n >= N_) return;
    int st = nodeptr[n], en = nodeptr[n + 1];
    float acc = (q == 0) ? tv[n] : 0.0f;
    int e = st + q;
    for (; e + 8 < en; e += 16) {         // 2 edges per iter (stride 8)
        int2 q0 = srec[e], q1 = srec[e + 8];
        float t0 = tv[q0.x], t1 = tv[q1.x];
        acc = fmaf(__int_as_float(q0.y), t0, acc);
        acc = fmaf(__int_as_float(q1.y), t1, acc);
    }
    if (e < en) {
        int2 qq = srec[e];
        acc = fmaf(__int_as_float(qq.y), tv[qq.x], acc);
    }
    acc += __shfl_xor(acc, 1);
    acc += __shfl_xor(acc, 2);
    acc += __shfl_xor(acc, 4);
    if (q == 0) out[n] = b2[0] + dinv[n] * acc;
}

extern "C" void kernel_launch(void* const* d_in, const int* in_sizes, int n_in,
                              void* d_out, int out_size, void* d_ws, size_t ws_size,
                              hipStream_t stream) {
    const float* x  = (const float*)d_in[0];
    const int*   ei = (const int*)d_in[1];    // [2, E] int32
    const float* w  = (const float*)d_in[2];
    const float* W1 = (const float*)d_in[3];
    const float* b1 = (const float*)d_in[4];
    const float* W2 = (const float*)d_in[5];
    const float* b2 = (const float*)d_in[6];
    float* out = (float*)d_out;

    const int* row = ei;
    const int* col = ei + E_;

    // ws (ints): countsA[1024000] | countsP[1024000] | grptot[20480] |
    //   baseB[2049 pad 2560] | nodeptr[100352] | dinv[N] | xw[8N] | tv[N] |
    //   brec[E] int2 | srt[E] int2                         ~64 MB
    int*   wsI     = (int*)d_ws;
    int*   countsA = wsI;
    int*   countsP = wsI + (size_t)CA * BK;          // 1024000
    int*   grptot  = countsP + (size_t)CA * BK;      // +1024000
    int*   baseB   = grptot + GG * BK;               // +20480
    int*   nodeptr = baseB + 2560;
    float* dinv    = (float*)(nodeptr + 100352);
    float* xw      = dinv + N_;
    float* tv      = xw + (size_t)8 * N_;
    int2*  brec    = (int2*)(tv + N_);
    int2*  srt     = brec + E_;

    kA_hist    <<<CA, 512, 0, stream>>>(col, countsA);
    kA_scan1   <<<(GG * BK + 255) / 256, 256, 0, stream>>>(countsA, countsP, grptot);
    kA_scan2B  <<<1, 1024, 0, stream>>>(grptot, baseB);
    kA_scatter2<<<CA, 512, 0, stream>>>(row, col, w, countsA, countsP, grptot, brec);
    kB_sortdeg <<<NBUCK, 512, 0, stream>>>(baseB, brec, srt, x, dinv, xw, nodeptr);
    kB2_node   <<<NBUCK, 512, 0, stream>>>(nodeptr, srt, dinv, xw, W1, b1, W2, tv);
    kB3_node   <<<NBUCK, 512, 0, stream>>>(nodeptr, srt, dinv, tv, b2, out);
}